// Round 14
// baseline (585.599 us; speedup 1.0000x reference)
//
#include <hip/hip_runtime.h>
#include <hip/hip_bf16.h>
#include <hip/hip_cooperative_groups.h>

namespace cg = cooperative_groups;

using bf = __hip_bfloat16;
typedef __attribute__((ext_vector_type(8))) short s8;
typedef __attribute__((ext_vector_type(4))) float f4;

constexpr int NN  = 32768;
constexpr int HD  = 256;

__device__ __forceinline__ float u2f(unsigned short h) {
    union { unsigned u; float f; } x; x.u = ((unsigned)h) << 16;
    return x.f;
}
__device__ __forceinline__ unsigned short f2u(float f) {
    union { float f; unsigned u; } x; x.f = f;
    unsigned r = x.u + 0x7FFF + ((x.u >> 16) & 1);
    return (unsigned short)(r >> 16);
}
__device__ __forceinline__ bf f2bf(float f) {
    unsigned short h = f2u(f);
    return *reinterpret_cast<bf*>(&h);
}
__device__ __forceinline__ float bf2f(bf b) {
    return u2f(*reinterpret_cast<unsigned short*>(&b));
}

__device__ __forceinline__ int swz(int row, int slot) {      // 64-col rows
    return row * 64 + ((slot ^ (row & 7)) << 3);
}
__device__ __forceinline__ int swz128(int row, int slot) {   // 128-col rows
    return row * 128 + ((slot ^ (row & 7)) << 3);
}

// ---------------- prep: adjacency + weight transpose + x cvt ----------------
struct WTd { const float* src; int K, N, off; };
struct WTpack { WTd w[10]; };

__global__ __launch_bounds__(256) void k_prep(const int* __restrict__ srcL,
                                              const int* __restrict__ dstL,
                                              const float* __restrict__ xf,
                                              WTpack p, bf* __restrict__ A,
                                              bf* __restrict__ xb,
                                              bf* __restrict__ wT) {
    __shared__ __align__(16) float shm[8320];
    int b = blockIdx.x, t = threadIdx.x;
    if (b < 256) {
        float* sT = shm;
        float* sdin = shm + 8192;
        int g = b;
        const int* sg = srcL + (g << 11);
        const int* dg = dstL + (g << 11);
        if (t < 128) sdin[t] = 0.f;
        __syncthreads();
        for (int e = t; e < 2048; e += 256) atomicAdd(&sdin[dg[e]], 1.0f);
        __syncthreads();
        if (t < 128) sdin[t] = rsqrtf(sdin[t] + 1.0f);
        __syncthreads();
        bf* out = A + ((long)g << 14);
        for (int half = 0; half < 2; ++half) {
            for (int i = t; i < 8192; i += 256) sT[i] = 0.f;
            __syncthreads();
            for (int e = t; e < 2048; e += 256) {
                int s = sg[e], d = dg[e];
                if ((s >> 6) == half)
                    atomicAdd(&sT[(d << 6) + (s & 63)], sdin[s] * sdin[d]);
            }
            __syncthreads();
            if (t < 128 && (t >> 6) == half)
                sT[(t << 6) + (t & 63)] += sdin[t] * sdin[t];
            __syncthreads();
            for (int i4 = t; i4 < 2048; i4 += 256) {
                int d = i4 >> 4, c4 = (i4 & 15) * 4;
                float4 v = *(float4*)&sT[(d << 6) + c4];
                ushort4 u = make_ushort4(f2u(v.x), f2u(v.y), f2u(v.z), f2u(v.w));
                *(ushort4*)&out[(d << 7) + (half << 6) + c4] = u;
            }
            __syncthreads();
        }
    } else if (b < 416) {
        int idx = b - 256;
        WTd d = p.w[idx >> 4];
        int rem = idx & 15;
        int n0 = (rem & 3) * 64, k0 = (rem >> 2) * 64;
        if (n0 >= d.N || k0 >= d.K) return;
        float (*s)[65] = (float(*)[65])shm;
        int cc = t & 63, rq = t >> 6;
#pragma unroll
        for (int i = 0; i < 16; ++i) {
            int r = i * 4 + rq;
            s[r][cc] = d.src[(long)(k0 + r) * d.N + n0 + cc];
        }
        __syncthreads();
#pragma unroll
        for (int i = 0; i < 16; ++i) {
            int r = i * 4 + rq;
            wT[d.off + (long)(n0 + r) * d.K + k0 + cc] = f2bf(s[cc][r]);
        }
    } else {
        long base = (long)(b - 416) * 16384;
#pragma unroll
        for (int it = 0; it < 16; ++it) {
            long i4 = base + (it * 256 + t) * 4;
            float4 v = *(const float4*)&xf[i4];
            *(ushort4*)&xb[i4] = make_ushort4(f2u(v.x), f2u(v.y), f2u(v.z), f2u(v.w));
        }
    }
}

// ---------------- MFMA helpers (512-thr per-graph kernels) ----------------
__device__ __forceinline__ void mfma_s1(const bf* sA, const bf* sB, f4 (&acc)[4][2],
                                        int wm, int wn, int l15, int kq) {
#pragma unroll
    for (int ks = 0; ks < 2; ++ks) {
        s8 af[4], bg[2];
#pragma unroll
        for (int f = 0; f < 4; ++f)
            af[f] = *(const s8*)&sA[swz(wm * 64 + f * 16 + l15, kq + 4 * ks)];
#pragma unroll
        for (int f = 0; f < 2; ++f)
            bg[f] = *(const s8*)&sB[swz(wn * 32 + f * 16 + l15, kq + 4 * ks)];
#pragma unroll
        for (int fr = 0; fr < 4; ++fr)
#pragma unroll
            for (int fc = 0; fc < 2; ++fc)
                acc[fr][fc] = __builtin_amdgcn_mfma_f32_16x16x32_bf16(
                    af[fr], bg[fc], acc[fr][fc], 0, 0, 0);
    }
}

__device__ __forceinline__ void mfma_s2(const bf* sA, const bf* sB, f4 (&acc)[4][2],
                                        int wm, int wn, int l15, int kq) {
#pragma unroll
    for (int ks = 0; ks < 4; ++ks) {
        s8 af[4], bg[2];
#pragma unroll
        for (int f = 0; f < 4; ++f)
            af[f] = *(const s8*)&sA[swz128(wm * 64 + f * 16 + l15, ks * 4 + kq)];
#pragma unroll
        for (int f = 0; f < 2; ++f)
            bg[f] = *(const s8*)&sB[swz128(wn * 32 + f * 16 + l15, ks * 4 + kq)];
#pragma unroll
        for (int fr = 0; fr < 4; ++fr)
#pragma unroll
            for (int fc = 0; fc < 2; ++fc)
                acc[fr][fc] = __builtin_amdgcn_mfma_f32_16x16x32_bf16(
                    af[fr], bg[fc], acc[fr][fc], 0, 0, 0);
    }
}

__device__ __forceinline__ void tstore(bf* sOut, f4 (&acc)[4][2],
                                       int wm, int wn, int l15, int kq) {
#pragma unroll
    for (int fr = 0; fr < 4; ++fr) {
        int rl = wm * 64 + fr * 16 + kq * 4;
#pragma unroll
        for (int fc = 0; fc < 2; ++fc) {
            int cl = wn * 32 + fc * 16 + l15;
            ushort4 q = make_ushort4(f2u(acc[fr][fc][0]), f2u(acc[fr][fc][1]),
                                     f2u(acc[fr][fc][2]), f2u(acc[fr][fc][3]));
            int off = cl * 128 + (((rl >> 3) ^ (cl & 7)) << 3) + (rl & 7);
            *(ushort4*)&sOut[off] = q;
        }
    }
}

__device__ __forceinline__ void stageAdj(bf* sStg, const bf* Adj, int g, int t) {
#pragma unroll
    for (int i = 0; i < 4; ++i) {
        int sdx = i * 512 + t;
        int row = sdx >> 4, sl = sdx & 15;
        *(s8*)&sStg[swz128(row, sl)] =
            *(const s8*)&Adj[((long)g << 14) + row * 128 + sl * 8];
    }
}

__device__ __forceinline__ void ag_part(f4 (&acc2)[4][2], bf* AG, float* part,
                                        bf* sStg, int g, int h, int t,
                                        int wm, int wn, int l15, int kq, int lane) {
    float ps[2] = {0.f, 0.f}, ps2[2] = {0.f, 0.f};
#pragma unroll
    for (int fr = 0; fr < 4; ++fr) {
        int rl = wm * 64 + fr * 16 + kq * 4;
#pragma unroll
        for (int fc = 0; fc < 2; ++fc) {
            int cl = wn * 32 + fc * 16 + l15;
#pragma unroll
            for (int i = 0; i < 4; ++i) {
                float v = acc2[fr][fc][i];
                ps[fc] += v; ps2[fc] += v * v;
                AG[(long)(g * 128 + rl + i) * 256 + h * 128 + cl] = f2bf(v);
            }
        }
    }
    __syncthreads();
    float* scr = (float*)sStg;
#pragma unroll
    for (int fc = 0; fc < 2; ++fc) {
        ps[fc] += __shfl_xor(ps[fc], 16);  ps[fc] += __shfl_xor(ps[fc], 32);
        ps2[fc] += __shfl_xor(ps2[fc], 16); ps2[fc] += __shfl_xor(ps2[fc], 32);
    }
    if (lane < 16) {
#pragma unroll
        for (int fc = 0; fc < 2; ++fc) {
            int c = wn * 32 + fc * 16 + lane;
            scr[(c * 2 + wm) * 2 + 0] = ps[fc];
            scr[(c * 2 + wm) * 2 + 1] = ps2[fc];
        }
    }
    __syncthreads();
    if (t < 256) {
        int col = t & 127, s = t >> 7;
        part[(long)(h * 256 + g) * 256 + s * 128 + col] =
            scr[(col * 2 + 0) * 2 + s] + scr[(col * 2 + 1) * 2 + s];
    }
}

// GCN layer phase: Z = relu(relu(X*sc+sh)+Res) on staging; AG = Adj@(Z@W)
__device__ __forceinline__ void gcn_layer(const bf* Xg, const bf* Rg,
                                          const float* stats, const bf* W,
                                          const bf* Adj, bf* Zout, bf* AG,
                                          float* part, bf* sOut, bf* sStg,
                                          int g, int h, int t, int lane,
                                          int wm, int wn, int l15, int kq) {
    f4 acc1[4][2] = {};
    for (int k0 = 0; k0 < 256; k0 += 64) {
        __syncthreads();
#pragma unroll
        for (int i = 0; i < 2; ++i) {
            int sdx = i * 512 + t;
            int row = sdx >> 3, sl = sdx & 7;
            int c = k0 + sl * 8;
            s8 av = *(const s8*)&Xg[row * 256 + c];
            s8 rv = *(const s8*)&Rg[row * 256 + c];
            float4 sc0 = *(const float4*)&stats[c];
            float4 sc1 = *(const float4*)&stats[c + 4];
            float4 sh0 = *(const float4*)&stats[256 + c];
            float4 sh1 = *(const float4*)&stats[256 + c + 4];
            float scv[8] = {sc0.x, sc0.y, sc0.z, sc0.w, sc1.x, sc1.y, sc1.z, sc1.w};
            float shv[8] = {sh0.x, sh0.y, sh0.z, sh0.w, sh1.x, sh1.y, sh1.z, sh1.w};
            unsigned short* u = (unsigned short*)&av;
            const unsigned short* ru = (const unsigned short*)&rv;
#pragma unroll
            for (int j = 0; j < 8; ++j) {
                float v = fmaf(u2f(u[j]), scv[j], shv[j]);
                v = fmaxf(v, 0.f) + u2f(ru[j]);
                u[j] = f2u(fmaxf(v, 0.f));
            }
            if (Zout) *(s8*)&Zout[(long)g * 32768 + row * 256 + c] = av;
            *(s8*)&sStg[swz(row, sl)] = av;
            *(s8*)&sStg[8192 + swz(row, sl)] = *(const s8*)&W[(h * 128 + row) * 256 + c];
        }
        __syncthreads();
        mfma_s1(sStg, sStg + 8192, acc1, wm, wn, l15, kq);
    }
    tstore(sOut, acc1, wm, wn, l15, kq);
    __syncthreads();
    stageAdj(sStg, Adj, g, t);
    __syncthreads();
    f4 acc2[4][2] = {};
    mfma_s2(sStg, sOut, acc2, wm, wn, l15, kq);
    ag_part(acc2, AG, part, sStg, g, h, t, wm, wn, l15, kq, lane);
}

// layer-0 GCN half (K=128, bf16 x)
__device__ __forceinline__ void l0_gcn(const bf* Xg, const bf* W0, const bf* Adj,
                                       bf* AG, float* part, bf* sOut, bf* sStg,
                                       int g, int h, int t, int lane,
                                       int wm, int wn, int l15, int kq) {
    f4 acc1[4][2] = {};
    for (int k0 = 0; k0 < 128; k0 += 64) {
        __syncthreads();
#pragma unroll
        for (int i = 0; i < 2; ++i) {
            int sdx = i * 512 + t;
            int row = sdx >> 3, sl = sdx & 7;
            int c = k0 + sl * 8;
            *(s8*)&sStg[swz(row, sl)] = *(const s8*)&Xg[row * 128 + c];
            *(s8*)&sStg[8192 + swz(row, sl)] = *(const s8*)&W0[(h * 128 + row) * 128 + c];
        }
        __syncthreads();
        mfma_s1(sStg, sStg + 8192, acc1, wm, wn, l15, kq);
    }
    tstore(sOut, acc1, wm, wn, l15, kq);
    __syncthreads();
    stageAdj(sStg, Adj, g, t);
    __syncthreads();
    f4 acc2[4][2] = {};
    mfma_s2(sStg, sOut, acc2, wm, wn, l15, kq);
    ag_part(acc2, AG, part, sStg, g, h, t, wm, wn, l15, kq, lane);
}

// layer-0 shortcut half: ResOut = x @ scW^T + b
__device__ __forceinline__ void l0_sc(const bf* Xg, const bf* Wsc, const float* scb,
                                      bf* ResOut, bf* sStg, int g, int h, int t,
                                      int wm, int wn, int l15, int kq) {
    f4 acc1[4][2] = {};
    for (int k0 = 0; k0 < 128; k0 += 64) {
        __syncthreads();
#pragma unroll
        for (int i = 0; i < 2; ++i) {
            int sdx = i * 512 + t;
            int row = sdx >> 3, sl = sdx & 7;
            int c = k0 + sl * 8;
            *(s8*)&sStg[swz(row, sl)] = *(const s8*)&Xg[row * 128 + c];
            *(s8*)&sStg[8192 + swz(row, sl)] = *(const s8*)&Wsc[(h * 128 + row) * 128 + c];
        }
        __syncthreads();
        mfma_s1(sStg, sStg + 8192, acc1, wm, wn, l15, kq);
    }
#pragma unroll
    for (int fr = 0; fr < 4; ++fr) {
        int rl = wm * 64 + fr * 16 + kq * 4;
#pragma unroll
        for (int fc = 0; fc < 2; ++fc) {
            int cl = wn * 32 + fc * 16 + l15;
            float bv = scb[h * 128 + cl];
#pragma unroll
            for (int i = 0; i < 4; ++i)
                ResOut[(long)(g * 128 + rl + i) * 256 + h * 128 + cl] =
                    f2bf(acc1[fr][fc][i] + bv);
        }
    }
}

__device__ __forceinline__ void bnfin_inline(const float* part, const float* gam,
                                             const float* bet, float* stats,
                                             void* lds, int ch, int t) {
    float2* sm = (float2*)lds;
    int half = ch >> 7, cc = ch & 127;
    if (t < 256) {
        const float* p = part + (long)(half * 256 + t) * 256;
        sm[t] = make_float2(p[cc], p[128 + cc]);
    }
    __syncthreads();
    for (int s = 128; s > 0; s >>= 1) {
        if (t < s) { sm[t].x += sm[t + s].x; sm[t].y += sm[t + s].y; }
        __syncthreads();
    }
    if (t == 0) {
        float m = sm[0].x / (float)NN;
        float var = sm[0].y / (float)NN - m * m;
        float sc = rsqrtf(var + 1e-5f) * gam[ch];
        stats[ch]       = sc;
        stats[256 + ch] = bet[ch] - m * sc;
    }
}

__device__ __forceinline__ void finz_inline(const bf* X, const float* stats,
                                            const bf* res, float* outz, bf* Znb,
                                            unsigned* zgu, float* pmLds,
                                            int g, int half, int t) {
    int lane = t & 63, w = t >> 6;
    int c4 = lane * 4;
    float4 sc = *(const float4*)&stats[c4];
    float4 sh = *(const float4*)&stats[256 + c4];
    float scv[4] = {sc.x, sc.y, sc.z, sc.w};
    float shv[4] = {sh.x, sh.y, sh.z, sh.w};
    float cmax[4] = {0.f, 0.f, 0.f, 0.f};
#pragma unroll
    for (int it = 0; it < 8; ++it) {
        int r = half * 64 + w * 8 + it;
        long i = (long)(g * 128 + r) * 256 + c4;
        ushort4 xv = *(const ushort4*)(X + i);
        ushort4 rv = *(const ushort4*)(res + i);
        unsigned short xs[4] = {xv.x, xv.y, xv.z, xv.w};
        unsigned short rs[4] = {rv.x, rv.y, rv.z, rv.w};
        float v[4];
        float s = 0.f;
#pragma unroll
        for (int j = 0; j < 4; ++j) {
            float vv = fmaf(u2f(xs[j]), scv[j], shv[j]);
            vv = fmaxf(vv, 0.f) + u2f(rs[j]);
            vv = fmaxf(vv, 0.f);
            v[j] = vv;
            s += vv * vv;
        }
#pragma unroll
        for (int o = 1; o < 64; o <<= 1) s += __shfl_xor(s, o);
        float den = fmaxf(sqrtf(s), 1e-12f);
        float4 fo;
        unsigned short us[4];
#pragma unroll
        for (int j = 0; j < 4; ++j) {
            float o = v[j] / den;
            ((float*)&fo)[j] = o;
            us[j] = f2u(o);
            cmax[j] = fmaxf(cmax[j], o);
        }
        *(float4*)(outz + i) = fo;
        *(ushort4*)(Znb + i) = make_ushort4(us[0], us[1], us[2], us[3]);
    }
    float (*pm)[256] = (float(*)[256])pmLds;
    __syncthreads();
#pragma unroll
    for (int j = 0; j < 4; ++j) pm[w][c4 + j] = cmax[j];
    __syncthreads();
    if (t < 256) {
        float m = pm[0][t];
#pragma unroll
        for (int ww = 1; ww < 8; ++ww) m = fmaxf(m, pm[ww][t]);
        atomicMax(&zgu[g * 256 + t], __float_as_uint(m));
    }
}

// ---------------- cooperative trunk ----------------
struct TrunkArgs {
    const bf* xb; const bf* Adj; const bf* wT;
    const float* scb;
    const float* g0; const float* be0;
    const float* g1; const float* be1;
    const float* g2; const float* be2;
    bf* U1; bf* U2; bf* U3; bf* U4;
    float* part; float* stats;
    float* outz; unsigned* zgu;
};

__global__ __launch_bounds__(512, 4) void k_trunk(TrunkArgs a) {
    __shared__ __align__(16) bf sOut[16384];
    __shared__ __align__(16) bf sStg[16384];
    cg::grid_group gg = cg::this_grid();
    const int b = blockIdx.x;
    const int g = b & 255, hs = b >> 8;
    const int t = threadIdx.x;
    const int lane = t & 63, w = t >> 6;
    const int wm = w >> 2, wn = w & 3;
    const int l15 = lane & 15, kq = lane >> 4;

    {
        const bf* Xg = a.xb + (long)g * 16384;
        l0_gcn(Xg, a.wT, a.Adj, a.U2, a.part, sOut, sStg,
               g, hs, t, lane, wm, wn, l15, kq);
        l0_sc(Xg, a.wT + 32768, a.scb, a.U1, sStg, g, hs, t, wm, wn, l15, kq);
    }
    gg.sync();
    if (hs == 0) bnfin_inline(a.part, a.g0, a.be0, a.stats, sStg, g, t);
    gg.sync();

    gcn_layer(a.U2 + (long)g * 32768, a.U1 + (long)g * 32768, a.stats,
              a.wT + 65536, a.Adj, hs == 0 ? a.U3 : nullptr, a.U4, a.part,
              sOut, sStg, g, hs, t, lane, wm, wn, l15, kq);
    gg.sync();
    if (hs == 0) bnfin_inline(a.part, a.g1, a.be1, a.stats, sStg, g, t);
    gg.sync();

    gcn_layer(a.U4 + (long)g * 32768, a.U3 + (long)g * 32768, a.stats,
              a.wT + 131072, a.Adj, hs == 0 ? a.U1 : nullptr, a.U2, a.part,
              sOut, sStg, g, hs, t, lane, wm, wn, l15, kq);
    gg.sync();
    if (hs == 0) bnfin_inline(a.part, a.g2, a.be2, a.stats, sStg, g, t);
    gg.sync();

    finz_inline(a.U2, a.stats, a.U1, a.outz, a.U3, a.zgu, (float*)sStg, g, hs, t);
}

// ---------------- fallback standalone trunk kernels ----------------
__global__ __launch_bounds__(512) void k_fall0(
    const bf* __restrict__ xb, const bf* __restrict__ W0, const bf* __restrict__ Wsc,
    const float* __restrict__ scb, const bf* __restrict__ Adj,
    bf* __restrict__ AG, bf* __restrict__ ResOut, float* __restrict__ part) {
    __shared__ __align__(16) bf sOut[16384];
    __shared__ __align__(16) bf sStg[16384];
    const int g = blockIdx.x, h = blockIdx.y;
    const int t = threadIdx.x;
    const int lane = t & 63, w = t >> 6;
    const int wm = w >> 2, wn = w & 3;
    const int l15 = lane & 15, kq = lane >> 4;
    const bf* Xg = xb + (long)g * 16384;
    if (h < 2)
        l0_gcn(Xg, W0, Adj, AG, part, sOut, sStg, g, h, t, lane, wm, wn, l15, kq);
    else
        l0_sc(Xg, Wsc, scb, ResOut, sStg, g, h - 2, t, wm, wn, l15, kq);
}

__global__ __launch_bounds__(512) void k_fall(
    const bf* __restrict__ Xin, const bf* __restrict__ Res,
    const float* __restrict__ stats, const bf* __restrict__ Wt,
    const bf* __restrict__ Adj, bf* __restrict__ Zout, bf* __restrict__ AG,
    float* __restrict__ part) {
    __shared__ __align__(16) bf sOut[16384];
    __shared__ __align__(16) bf sStg[16384];
    const int g = blockIdx.x, h = blockIdx.y;
    const int t = threadIdx.x;
    const int lane = t & 63, w = t >> 6;
    const int wm = w >> 2, wn = w & 3;
    const int l15 = lane & 15, kq = lane >> 4;
    gcn_layer(Xin + (long)g * 32768, Res + (long)g * 32768, stats, Wt, Adj,
              h == 0 ? Zout : nullptr, AG, part, sOut, sStg,
              g, h, t, lane, wm, wn, l15, kq);
}

__global__ void k_bnfin(const float* __restrict__ part, const float* __restrict__ gam,
                        const float* __restrict__ bet, float* __restrict__ stats) {
    int ch = blockIdx.x;
    int half = ch >> 7, cc = ch & 127;
    int t = threadIdx.x;
    __shared__ float2 sm[256];
    const float* p = part + (long)(half * 256 + t) * 256;
    sm[t] = make_float2(p[cc], p[128 + cc]);
    __syncthreads();
    for (int s = 128; s > 0; s >>= 1) {
        if (t < s) { sm[t].x += sm[t + s].x; sm[t].y += sm[t + s].y; }
        __syncthreads();
    }
    if (t == 0) {
        float m = sm[0].x / (float)NN;
        float var = sm[0].y / (float)NN - m * m;
        float sc = rsqrtf(var + 1e-5f) * gam[ch];
        stats[ch]       = sc;
        stats[256 + ch] = bet[ch] - m * sc;
    }
}

__global__ __launch_bounds__(512) void k_finz(
    const bf* __restrict__ X, const float* __restrict__ stats,
    const bf* __restrict__ res, float* __restrict__ outz, bf* __restrict__ Znb,
    unsigned* __restrict__ zgu) {
    __shared__ float pm[8][256];
    finz_inline(X, stats, res, outz, Znb, zgu, (float*)pm,
                blockIdx.x, blockIdx.y, threadIdx.x);
}

// ---------------- fd stage-1 layer (device fn, used by k_edfd) ----------------
__device__ __forceinline__ void fd_layer(const bf* Zg, const bf* W, const float* bias,
                                         bf* C, float* part, bf* sStg,
                                         int g, int h, int t, int lane,
                                         int wm, int wn, int l15, int kq) {
    f4 acc[4][2] = {};
    for (int k0 = 0; k0 < 256; k0 += 64) {
        __syncthreads();
#pragma unroll
        for (int i = 0; i < 2; ++i) {
            int sdx = i * 512 + t;
            int row = sdx >> 3, sl = sdx & 7;
            int c = k0 + sl * 8;
            *(s8*)&sStg[swz(row, sl)] = *(const s8*)&Zg[row * 256 + c];
            *(s8*)&sStg[8192 + swz(row, sl)] = *(const s8*)&W[(h * 128 + row) * 256 + c];
        }
        __syncthreads();
        mfma_s1(sStg, sStg + 8192, acc, wm, wn, l15, kq);
    }
    float ps[2] = {0.f, 0.f}, ps2[2] = {0.f, 0.f};
#pragma unroll
    for (int fr = 0; fr < 4; ++fr) {
        int rl = wm * 64 + fr * 16 + kq * 4;
#pragma unroll
        for (int fc = 0; fc < 2; ++fc) {
            int cl = wn * 32 + fc * 16 + l15;
            float bv = bias[h * 128 + cl];
#pragma unroll
            for (int i = 0; i < 4; ++i) {
                float v = fmaxf(acc[fr][fc][i] + bv, 0.f);
                ps[fc] += v; ps2[fc] += v * v;
                C[(long)(g * 128 + rl + i) * 256 + h * 128 + cl] = f2bf(v);
            }
        }
    }
    __syncthreads();
    float* scr = (float*)sStg;
#pragma unroll
    for (int fc = 0; fc < 2; ++fc) {
        ps[fc] += __shfl_xor(ps[fc], 16);  ps[fc] += __shfl_xor(ps[fc], 32);
        ps2[fc] += __shfl_xor(ps2[fc], 16); ps2[fc] += __shfl_xor(ps2[fc], 32);
    }
    if (lane < 16) {
#pragma unroll
        for (int fc = 0; fc < 2; ++fc) {
            int c = wn * 32 + fc * 16 + lane;
            scr[(c * 2 + wm) * 2 + 0] = ps[fc];
            scr[(c * 2 + wm) * 2 + 1] = ps2[fc];
        }
    }
    __syncthreads();
    if (t < 256) {
        int col = t & 127, s = t >> 7;
        part[(long)(h * 256 + g) * 256 + s * 128 + col] =
            scr[(col * 2 + 0) * 2 + s] + scr[(col * 2 + 1) * 2 + s];
    }
}

// ---------------- edge decoder + fd0, one dispatch (768 blocks) ----------------
__global__ __launch_bounds__(512) void k_edfd(
    const bf* __restrict__ Zn, const bf* __restrict__ ewT,
    const bf* __restrict__ fdw, const float* __restrict__ fdb,
    float* __restrict__ adjout, bf* __restrict__ C, float* __restrict__ part) {
    __shared__ __align__(16) bf sOut[16384];
    __shared__ __align__(16) bf sStg[16384];
    const int t = threadIdx.x;
    const int lane = t & 63, w = t >> 6;
    const int wm = w >> 2, wn = w & 3;
    const int l15 = lane & 15, kq = lane >> 4;
    if (blockIdx.x >= 256) {
        int bb = blockIdx.x - 256;
        int g = bb & 255, h = bb >> 8;
        fd_layer(Zn + (long)g * 32768, fdw, fdb, C, part, sStg,
                 g, h, t, lane, wm, wn, l15, kq);
        return;
    }
    const int g = blockIdx.x;
    const bf* Xg = Zn + (long)g * 32768;
    f4 acc2[4][2] = {};
    for (int h = 0; h < 2; ++h) {
        f4 acc1[4][2] = {};
        for (int k0 = 0; k0 < 256; k0 += 64) {
            __syncthreads();
#pragma unroll
            for (int i = 0; i < 2; ++i) {
                int sdx = i * 512 + t;
                int row = sdx >> 3, sl = sdx & 7;
                int c = k0 + sl * 8;
                *(s8*)&sStg[swz(row, sl)] = *(const s8*)&ewT[(h * 128 + row) * 256 + c];
                *(s8*)&sStg[8192 + swz(row, sl)] = *(const s8*)&Xg[row * 256 + c];
            }
            __syncthreads();
            mfma_s1(sStg, sStg + 8192, acc1, wm, wn, l15, kq);
        }
        tstore(sOut, acc1, wm, wn, l15, kq);
        __syncthreads();
#pragma unroll
        for (int i = 0; i < 4; ++i) {
            int sdx = i * 512 + t;
            int row = sdx >> 4, sl = sdx & 15;
            *(s8*)&sStg[swz128(row, sl)] = *(const s8*)&Xg[row * 256 + h * 128 + sl * 8];
        }
        __syncthreads();
        mfma_s2(sStg, sOut, acc2, wm, wn, l15, kq);
        __syncthreads();
    }
#pragma unroll
    for (int fr = 0; fr < 4; ++fr) {
        int rl = wm * 64 + fr * 16 + kq * 4;
#pragma unroll
        for (int fc = 0; fc < 2; ++fc) {
            int cl = wn * 32 + fc * 16 + l15;
            float vv[4];
#pragma unroll
            for (int i = 0; i < 4; ++i) {
                float v = 1.f / (1.f + __expf(-acc2[fr][fc][i]));
                if (cl == rl + i) v = 0.f;
                vv[i] = v;
            }
            float4 o; o.x = vv[0]; o.y = vv[1]; o.z = vv[2]; o.w = vv[3];
            *(float4*)&adjout[((long)g << 14) + cl * 128 + rl] = o;
        }
    }
}

// ---------------- MFMA GEMM (fd1/fd2/ph chains) ----------------
template <int EPI, int OUT, bool PART, bool BNA, bool AF32>
__global__ __launch_bounds__(256) void mg(
    const void* __restrict__ Av, const bf* __restrict__ BT,
    const float* __restrict__ bias, const float* __restrict__ bnstats,
    float* __restrict__ Cf, bf* __restrict__ Cb, float* __restrict__ part,
    int M, int N, int K, int ldc) {
    __shared__ __align__(16) bf sAl[128 * 64];
    __shared__ __align__(16) bf sBl[128 * 64];
    const int m0 = blockIdx.y * 128, n0 = blockIdx.x * 128;
    const bf* Bb = BT + (long)n0 * K;
    const int t = threadIdx.x;
    const int lane = t & 63;
    const int w = t >> 6;
    const int wm = (w >> 1) * 64, wn = (w & 1) * 64;
    const int fr16 = lane & 15, kq = lane >> 4;
    f4 acc[4][4] = {};
    for (int k0 = 0; k0 < K; k0 += 64) {
#pragma unroll
        for (int i = 0; i < 4; ++i) {
            int sdx = i * 256 + t;
            int row = sdx >> 3, sl = sdx & 7;
            s8 av;
            if constexpr (AF32) {
                const float* src = (const float*)Av + (long)(m0 + row) * K + k0 + sl * 8;
                float4 f0 = *(const float4*)src;
                float4 f1 = *(const float4*)(src + 4);
                unsigned short u[8] = {f2u(f0.x), f2u(f0.y), f2u(f0.z), f2u(f0.w),
                                       f2u(f1.x), f2u(f1.y), f2u(f1.z), f2u(f1.w)};
                av = *(s8*)u;
            } else {
                av = *(const s8*)&((const bf*)Av)[(long)(m0 + row) * K + k0 + sl * 8];
                if constexpr (BNA) {
                    int c = k0 + sl * 8;
                    float4 sc0 = *(const float4*)&bnstats[c];
                    float4 sc1 = *(const float4*)&bnstats[c + 4];
                    float4 sh0 = *(const float4*)&bnstats[256 + c];
                    float4 sh1 = *(const float4*)&bnstats[256 + c + 4];
                    float scv[8] = {sc0.x, sc0.y, sc0.z, sc0.w, sc1.x, sc1.y, sc1.z, sc1.w};
                    float shv[8] = {sh0.x, sh0.y, sh0.z, sh0.w, sh1.x, sh1.y, sh1.z, sh1.w};
                    unsigned short* u = (unsigned short*)&av;
#pragma unroll
                    for (int j = 0; j < 8; ++j)
                        u[j] = f2u(fmaf(u2f(u[j]), scv[j], shv[j]));
                }
            }
            *(s8*)&sAl[swz(row, sl)] = av;
            *(s8*)&sBl[swz(row, sl)] = *(const s8*)&Bb[(long)row * K + k0 + sl * 8];
        }
        __syncthreads();
#pragma unroll
        for (int ks = 0; ks < 2; ++ks) {
            s8 af[4], bg[4];
#pragma unroll
            for (int f = 0; f < 4; ++f) {
                af[f] = *(const s8*)&sAl[swz(wm + f * 16 + fr16, kq + 4 * ks)];
                bg[f] = *(const s8*)&sBl[swz(wn + f * 16 + fr16, kq + 4 * ks)];
            }
#pragma unroll
            for (int fr = 0; fr < 4; ++fr)
#pragma unroll
                for (int fc = 0; fc < 4; ++fc)
                    acc[fr][fc] = __builtin_amdgcn_mfma_f32_16x16x32_bf16(
                        af[fr], bg[fc], acc[fr][fc], 0, 0, 0);
        }
        __syncthreads();
    }
    float ps[4], ps2[4];
    if (PART) {
#pragma unroll
        for (int fc = 0; fc < 4; ++fc) { ps[fc] = 0.f; ps2[fc] = 0.f; }
    }
#pragma unroll
    for (int fr = 0; fr < 4; ++fr) {
        int rl = wm + fr * 16 + (lane >> 4) * 4;
#pragma unroll
        for (int fc = 0; fc < 4; ++fc) {
            int cl = wn + fc * 16 + (lane & 15);
            int col = n0 + cl;
            float bv = bias[col];
#pragma unroll
            for (int i = 0; i < 4; ++i) {
                float v = acc[fr][fc][i] + bv;
                if (EPI == 2) v = fmaxf(v, 0.f);
                if (PART) { ps[fc] += v; ps2[fc] += v * v; }
                if (OUT == 0) Cf[(long)(m0 + rl + i) * ldc + col] = v;
                if (OUT == 1) Cb[(long)(m0 + rl + i) * ldc + col] = f2bf(v);
            }
        }
    }
    if (PART) {
        __syncthreads();
        float* scr = (float*)sAl;
#pragma unroll
        for (int fc = 0; fc < 4; ++fc) {
            ps[fc] += __shfl_xor(ps[fc], 16);  ps[fc] += __shfl_xor(ps[fc], 32);
            ps2[fc] += __shfl_xor(ps2[fc], 16); ps2[fc] += __shfl_xor(ps2[fc], 32);
        }
        if (lane < 16) {
#pragma unroll
            for (int fc = 0; fc < 4; ++fc) {
                scr[(w * 2 + 0) * 64 + fc * 16 + lane] = ps[fc];
                scr[(w * 2 + 1) * 64 + fc * 16 + lane] = ps2[fc];
            }
        }
        __syncthreads();
        int id = blockIdx.x * gridDim.y + blockIdx.y;   // gridDim = (2, 256)
        int stat = t >> 7, c = t & 127;
        int ci = c & 63, half = c >> 6;
        float v = scr[(half * 2 + stat) * 64 + ci] + scr[((half + 2) * 2 + stat) * 64 + ci];
        part[(long)id * 256 + stat * 128 + c] = v;
    }
}

// ---------------- host ----------------
template <int EPI, int OUT, bool PART, bool BNA, bool AF32>
static void MG(hipStream_t st, const void* A, const bf* BT, const float* bias,
               const float* bnstats, float* Cf, bf* Cb, float* part,
               int M, int N, int K, int ldc) {
    dim3 g(N / 128, M / 128, 1);
    mg<EPI, OUT, PART, BNA, AF32><<<g, 256, 0, st>>>(A, BT, bias, bnstats, Cf, Cb, part,
                                                     M, N, K, ldc);
}

extern "C" void kernel_launch(void* const* d_in, const int* in_sizes, int n_in,
                              void* d_out, int out_size, void* d_ws, size_t ws_size,
                              hipStream_t stream) {
    const float* x      = (const float*)d_in[0];
    const int*   srcL   = (const int*)d_in[1];
    const int*   dstL   = (const int*)d_in[2];
    const float* gcn_w0 = (const float*)d_in[3];
    const float* bn_g0  = (const float*)d_in[5];
    const float* bn_b0  = (const float*)d_in[6];
    const float* gcn_w1 = (const float*)d_in[7];
    const float* bn_g1  = (const float*)d_in[9];
    const float* bn_b1  = (const float*)d_in[10];
    const float* gcn_w2 = (const float*)d_in[11];
    const float* bn_g2  = (const float*)d_in[13];
    const float* bn_b2  = (const float*)d_in[14];
    const float* sc_w0  = (const float*)d_in[15];
    const float* sc_b0  = (const float*)d_in[16];
    const float* edge_w = (const float*)d_in[17];
    const float* fd_w0  = (const float*)d_in[18];
    const float* fd_b0  = (const float*)d_in[19];
    const float* fd_g0  = (const float*)d_in[20];
    const float* fd_be0 = (const float*)d_in[21];
    const float* fd_w1  = (const float*)d_in[22];
    const float* fd_b1  = (const float*)d_in[23];
    const float* fd_g1  = (const float*)d_in[24];
    const float* fd_be1 = (const float*)d_in[25];
    const float* fd_w2  = (const float*)d_in[26];
    const float* fd_b2  = (const float*)d_in[27];
    const float* ph_w0  = (const float*)d_in[28];
    const float* ph_b0  = (const float*)d_in[29];
    const float* ph_w1  = (const float*)d_in[30];
    const float* ph_b1  = (const float*)d_in[31];

    float* out     = (float*)d_out;
    float* out_z   = out;
    float* out_adj = out + 8388608;
    float* out_xr  = out + 12582912;
    float* out_zg  = out + 16777216;
    float* out_zgm = out + 16842752;

    float* w     = (float*)d_ws;
    float* part  = w;                        // 131072
    float* stats = w + 131072;               // 512
    bf*    wT    = (bf*)(w + 131584);        // 557056 bf16
    bf*    Aadjb = (bf*)(w + 410112);        // 4194304 bf16
    bf*    U4    = (bf*)(w + 2507264);       // 8388608 bf16
    bf*    U1    = (bf*)(w + 6701568);       // 8388608 bf16
    bf*    U2    = (bf*)(w + 10895872);      // 8388608 bf16
    bf*    U3    = (bf*)(w + 15090176);      // 8388608 bf16
    bf*    P1b   = (bf*)(w + 19284480);      // 65536 bf16
    bf*    xb    = (bf*)(w + 19317248);      // 4194304 bf16

    WTpack pk;
    pk.w[0] = {gcn_w0, 128, 256, 0};
    pk.w[1] = {sc_w0,  128, 256, 32768};
    pk.w[2] = {gcn_w1, 256, 256, 65536};
    pk.w[3] = {gcn_w2, 256, 256, 131072};
    pk.w[4] = {edge_w, 256, 256, 196608};
    pk.w[5] = {fd_w0,  256, 256, 262144};
    pk.w[6] = {fd_w1,  256, 256, 327680};
    pk.w[7] = {fd_w2,  256, 128, 393216};
    pk.w[8] = {ph_w0,  256, 256, 425984};
    pk.w[9] = {ph_w1,  256, 256, 491520};

    // zero out_zg early (atomicMax target; harness poisons d_out)
    hipMemsetAsync(out_zg, 0, 65536 * 4, stream);

    // --- prep: adjacency + weight transpose + x->bf16 ---
    k_prep<<<672, 256, 0, stream>>>(srcL, dstL, x, pk, Aadjb, xb, wT);

    // --- trunk: try cooperative mega-kernel; fall back to multi-dispatch ---
    TrunkArgs ta;
    ta.xb = xb; ta.Adj = Aadjb; ta.wT = wT;
    ta.scb = sc_b0;
    ta.g0 = bn_g0; ta.be0 = bn_b0;
    ta.g1 = bn_g1; ta.be1 = bn_b1;
    ta.g2 = bn_g2; ta.be2 = bn_b2;
    ta.U1 = U1; ta.U2 = U2; ta.U3 = U3; ta.U4 = U4;
    ta.part = part; ta.stats = stats;
    ta.outz = out_z; ta.zgu = (unsigned*)out_zg;
    void* kargs[] = {&ta};
    hipError_t rc = hipLaunchCooperativeKernel(reinterpret_cast<void*>(k_trunk),
                                               dim3(512), dim3(512), kargs, 0, stream);
    if (rc != hipSuccess) {
        k_fall0<<<dim3(256, 4), 512, 0, stream>>>(xb, wT, wT + 32768, sc_b0, Aadjb,
                                                  U2, U1, part);
        k_bnfin<<<256, 256, 0, stream>>>(part, bn_g0, bn_b0, stats);
        k_fall<<<dim3(256, 2), 512, 0, stream>>>(U2, U1, stats, wT + 65536, Aadjb,
                                                 U3, U4, part);
        k_bnfin<<<256, 256, 0, stream>>>(part, bn_g1, bn_b1, stats);
        k_fall<<<dim3(256, 2), 512, 0, stream>>>(U4, U3, stats, wT + 131072, Aadjb,
                                                 U1, U2, part);
        k_bnfin<<<256, 256, 0, stream>>>(part, bn_g2, bn_b2, stats);
        k_finz<<<dim3(256, 2), 512, 0, stream>>>(U2, stats, U1, out_z, U3,
                                                 (unsigned*)out_zg);
    }

    // --- edge decoder + fd0, one dispatch ---
    k_edfd<<<768, 512, 0, stream>>>(U3, wT + 196608, wT + 262144, fd_b0,
                                    out_adj, U4, part);
    k_bnfin<<<256, 256, 0, stream>>>(part, fd_g0, fd_be0, stats);

    // --- feature decoder (fd1, fd2) ---
    MG<2, 1, true, true, false>(stream, U4, wT + 327680, fd_b1, stats,
                                nullptr, U2, part, NN, HD, HD, 256);
    k_bnfin<<<256, 256, 0, stream>>>(part, fd_g1, fd_be1, stats);
    MG<1, 0, false, true, false>(stream, U2, wT + 393216, fd_b2, stats,
                                 out_xr, nullptr, nullptr, NN, 128, HD, 128);

    // --- pooling head (ph0 reads out_zg f32 directly) ---
    MG<2, 1, false, false, true>(stream, out_zg, wT + 425984, ph_b0, nullptr,
                                 nullptr, P1b, nullptr, 256, 256, 256, 256);
    MG<1, 0, false, false, false>(stream, P1b, wT + 491520, ph_b1, nullptr,
                                  out_zgm, nullptr, nullptr, 256, 256, 256, 256);
}

// Round 15
// 201.260 us; speedup vs baseline: 2.9097x; 2.9097x over previous
//
#include <hip/hip_runtime.h>
#include <hip/hip_bf16.h>

using bf = __hip_bfloat16;
typedef __attribute__((ext_vector_type(8))) short s8;
typedef __attribute__((ext_vector_type(4))) float f4;

constexpr int NN  = 32768;
constexpr int HD  = 256;

__device__ __forceinline__ float u2f(unsigned short h) {
    union { unsigned u; float f; } x; x.u = ((unsigned)h) << 16;
    return x.f;
}
__device__ __forceinline__ unsigned short f2u(float f) {
    union { float f; unsigned u; } x; x.f = f;
    unsigned r = x.u + 0x7FFF + ((x.u >> 16) & 1);
    return (unsigned short)(r >> 16);
}
__device__ __forceinline__ bf f2bf(float f) {
    unsigned short h = f2u(f);
    return *reinterpret_cast<bf*>(&h);
}
__device__ __forceinline__ float bf2f(bf b) {
    return u2f(*reinterpret_cast<unsigned short*>(&b));
}

__device__ __forceinline__ int swz(int row, int slot) {      // 64-col rows
    return row * 64 + ((slot ^ (row & 7)) << 3);
}
__device__ __forceinline__ int swz128(int row, int slot) {   // 128-col rows
    return row * 128 + ((slot ^ (row & 7)) << 3);
}

// ---------------- prep: adjacency + weight transpose + x cvt ----------------
struct WTd { const float* src; int K, N, off; };
struct WTpack { WTd w[10]; };

__global__ __launch_bounds__(256) void k_prep(const int* __restrict__ srcL,
                                              const int* __restrict__ dstL,
                                              const float* __restrict__ xf,
                                              WTpack p, bf* __restrict__ A,
                                              bf* __restrict__ xb,
                                              bf* __restrict__ wT) {
    __shared__ __align__(16) float shm[8320];
    int b = blockIdx.x, t = threadIdx.x;
    if (b < 256) {
        float* sT = shm;
        float* sdin = shm + 8192;
        int g = b;
        const int* sg = srcL + (g << 11);
        const int* dg = dstL + (g << 11);
        if (t < 128) sdin[t] = 0.f;
        __syncthreads();
        for (int e = t; e < 2048; e += 256) atomicAdd(&sdin[dg[e]], 1.0f);
        __syncthreads();
        if (t < 128) sdin[t] = rsqrtf(sdin[t] + 1.0f);
        __syncthreads();
        bf* out = A + ((long)g << 14);
        for (int half = 0; half < 2; ++half) {
            for (int i = t; i < 8192; i += 256) sT[i] = 0.f;
            __syncthreads();
            for (int e = t; e < 2048; e += 256) {
                int s = sg[e], d = dg[e];
                if ((s >> 6) == half)
                    atomicAdd(&sT[(d << 6) + (s & 63)], sdin[s] * sdin[d]);
            }
            __syncthreads();
            if (t < 128 && (t >> 6) == half)
                sT[(t << 6) + (t & 63)] += sdin[t] * sdin[t];
            __syncthreads();
            for (int i4 = t; i4 < 2048; i4 += 256) {
                int d = i4 >> 4, c4 = (i4 & 15) * 4;
                float4 v = *(float4*)&sT[(d << 6) + c4];
                ushort4 u = make_ushort4(f2u(v.x), f2u(v.y), f2u(v.z), f2u(v.w));
                *(ushort4*)&out[(d << 7) + (half << 6) + c4] = u;
            }
            __syncthreads();
        }
    } else if (b < 416) {
        int idx = b - 256;
        WTd d = p.w[idx >> 4];
        int rem = idx & 15;
        int n0 = (rem & 3) * 64, k0 = (rem >> 2) * 64;
        if (n0 >= d.N || k0 >= d.K) return;
        float (*s)[65] = (float(*)[65])shm;
        int cc = t & 63, rq = t >> 6;
#pragma unroll
        for (int i = 0; i < 16; ++i) {
            int r = i * 4 + rq;
            s[r][cc] = d.src[(long)(k0 + r) * d.N + n0 + cc];
        }
        __syncthreads();
#pragma unroll
        for (int i = 0; i < 16; ++i) {
            int r = i * 4 + rq;
            wT[d.off + (long)(n0 + r) * d.K + k0 + cc] = f2bf(s[cc][r]);
        }
    } else {
        long base = (long)(b - 416) * 16384;
#pragma unroll
        for (int it = 0; it < 16; ++it) {
            long i4 = base + (it * 256 + t) * 4;
            float4 v = *(const float4*)&xf[i4];
            *(ushort4*)&xb[i4] = make_ushort4(f2u(v.x), f2u(v.y), f2u(v.z), f2u(v.w));
        }
    }
}

// ---------------- in-kernel BN stat finalize ----------------
// 512-thr: thread t handles combo (ch = t&255, stat = t>>8); result: sS[0..255]=scale,
// sS[256..511]=shift. Deterministic (fixed sequential order, identical in every block).
__device__ __forceinline__ void stats512(const float* part, const float* gam,
                                         const float* bet, float* sS, int t) {
    int ch = t & 255, stat = t >> 8;
    int half = ch >> 7, cc = ch & 127;
    const float* p = part + (long)(half * 256) * 256 + stat * 128 + cc;
    float s = 0.f;
    for (int b = 0; b < 256; ++b) s += p[b * 256];
    sS[t] = s;
    __syncthreads();
    float sum = 0.f, sq = 0.f;
    if (t < 256) { sum = sS[t]; sq = sS[256 + t]; }
    __syncthreads();
    if (t < 256) {
        float m = sum / (float)NN;
        float var = sq / (float)NN - m * m;
        float sc = rsqrtf(var + 1e-5f) * gam[t];
        sS[t]       = sc;
        sS[256 + t] = bet[t] - m * sc;
    }
    __syncthreads();
}

// 256-thr variant: thread t handles channel t (both stats).
__device__ __forceinline__ void stats256(const float* part, const float* gam,
                                         const float* bet, float* sS, int t) {
    int half = t >> 7, cc = t & 127;
    const float* p = part + (long)(half * 256) * 256 + cc;
    float s = 0.f, s2 = 0.f;
    for (int b = 0; b < 256; ++b) { s += p[b * 256]; s2 += p[b * 256 + 128]; }
    float m = s / (float)NN;
    float var = s2 / (float)NN - m * m;
    float sc = rsqrtf(var + 1e-5f) * gam[t];
    sS[t]       = sc;
    sS[256 + t] = bet[t] - m * sc;
    __syncthreads();
}

// ---------------- MFMA helpers (512-thr per-graph kernels) ----------------
__device__ __forceinline__ void mfma_s1(const bf* sA, const bf* sB, f4 (&acc)[4][2],
                                        int wm, int wn, int l15, int kq) {
#pragma unroll
    for (int ks = 0; ks < 2; ++ks) {
        s8 af[4], bg[2];
#pragma unroll
        for (int f = 0; f < 4; ++f)
            af[f] = *(const s8*)&sA[swz(wm * 64 + f * 16 + l15, kq + 4 * ks)];
#pragma unroll
        for (int f = 0; f < 2; ++f)
            bg[f] = *(const s8*)&sB[swz(wn * 32 + f * 16 + l15, kq + 4 * ks)];
#pragma unroll
        for (int fr = 0; fr < 4; ++fr)
#pragma unroll
            for (int fc = 0; fc < 2; ++fc)
                acc[fr][fc] = __builtin_amdgcn_mfma_f32_16x16x32_bf16(
                    af[fr], bg[fc], acc[fr][fc], 0, 0, 0);
    }
}

__device__ __forceinline__ void mfma_s2(const bf* sA, const bf* sB, f4 (&acc)[4][2],
                                        int wm, int wn, int l15, int kq) {
#pragma unroll
    for (int ks = 0; ks < 4; ++ks) {
        s8 af[4], bg[2];
#pragma unroll
        for (int f = 0; f < 4; ++f)
            af[f] = *(const s8*)&sA[swz128(wm * 64 + f * 16 + l15, ks * 4 + kq)];
#pragma unroll
        for (int f = 0; f < 2; ++f)
            bg[f] = *(const s8*)&sB[swz128(wn * 32 + f * 16 + l15, ks * 4 + kq)];
#pragma unroll
        for (int fr = 0; fr < 4; ++fr)
#pragma unroll
            for (int fc = 0; fc < 2; ++fc)
                acc[fr][fc] = __builtin_amdgcn_mfma_f32_16x16x32_bf16(
                    af[fr], bg[fc], acc[fr][fc], 0, 0, 0);
    }
}

__device__ __forceinline__ void tstore(bf* sOut, f4 (&acc)[4][2],
                                       int wm, int wn, int l15, int kq) {
#pragma unroll
    for (int fr = 0; fr < 4; ++fr) {
        int rl = wm * 64 + fr * 16 + kq * 4;
#pragma unroll
        for (int fc = 0; fc < 2; ++fc) {
            int cl = wn * 32 + fc * 16 + l15;
            ushort4 q = make_ushort4(f2u(acc[fr][fc][0]), f2u(acc[fr][fc][1]),
                                     f2u(acc[fr][fc][2]), f2u(acc[fr][fc][3]));
            int off = cl * 128 + (((rl >> 3) ^ (cl & 7)) << 3) + (rl & 7);
            *(ushort4*)&sOut[off] = q;
        }
    }
}

__device__ __forceinline__ void stageAdj(bf* sStg, const bf* Adj, int g, int t) {
#pragma unroll
    for (int i = 0; i < 4; ++i) {
        int sdx = i * 512 + t;
        int row = sdx >> 4, sl = sdx & 15;
        *(s8*)&sStg[swz128(row, sl)] =
            *(const s8*)&Adj[((long)g << 14) + row * 128 + sl * 8];
    }
}

__device__ __forceinline__ void ag_part(f4 (&acc2)[4][2], bf* AG, float* part,
                                        bf* sStg, int g, int h, int t,
                                        int wm, int wn, int l15, int kq, int lane) {
    float ps[2] = {0.f, 0.f}, ps2[2] = {0.f, 0.f};
#pragma unroll
    for (int fr = 0; fr < 4; ++fr) {
        int rl = wm * 64 + fr * 16 + kq * 4;
#pragma unroll
        for (int fc = 0; fc < 2; ++fc) {
            int cl = wn * 32 + fc * 16 + l15;
#pragma unroll
            for (int i = 0; i < 4; ++i) {
                float v = acc2[fr][fc][i];
                ps[fc] += v; ps2[fc] += v * v;
                AG[(long)(g * 128 + rl + i) * 256 + h * 128 + cl] = f2bf(v);
            }
        }
    }
    __syncthreads();
    float* scr = (float*)sStg;
#pragma unroll
    for (int fc = 0; fc < 2; ++fc) {
        ps[fc] += __shfl_xor(ps[fc], 16);  ps[fc] += __shfl_xor(ps[fc], 32);
        ps2[fc] += __shfl_xor(ps2[fc], 16); ps2[fc] += __shfl_xor(ps2[fc], 32);
    }
    if (lane < 16) {
#pragma unroll
        for (int fc = 0; fc < 2; ++fc) {
            int c = wn * 32 + fc * 16 + lane;
            scr[(c * 2 + wm) * 2 + 0] = ps[fc];
            scr[(c * 2 + wm) * 2 + 1] = ps2[fc];
        }
    }
    __syncthreads();
    if (t < 256) {
        int col = t & 127, s = t >> 7;
        part[(long)(h * 256 + g) * 256 + s * 128 + col] =
            scr[(col * 2 + 0) * 2 + s] + scr[(col * 2 + 1) * 2 + s];
    }
}

// GCN layer phase: Z = relu(relu(X*sc+sh)+Res) on staging; AG = Adj@(Z@W)
// stats points to LDS (512 floats: scale | shift)
__device__ __forceinline__ void gcn_layer(const bf* Xg, const bf* Rg,
                                          const float* stats, const bf* W,
                                          const bf* Adj, bf* Zout, bf* AG,
                                          float* part, bf* sOut, bf* sStg,
                                          int g, int h, int t, int lane,
                                          int wm, int wn, int l15, int kq) {
    f4 acc1[4][2] = {};
    for (int k0 = 0; k0 < 256; k0 += 64) {
        __syncthreads();
#pragma unroll
        for (int i = 0; i < 2; ++i) {
            int sdx = i * 512 + t;
            int row = sdx >> 3, sl = sdx & 7;
            int c = k0 + sl * 8;
            s8 av = *(const s8*)&Xg[row * 256 + c];
            s8 rv = *(const s8*)&Rg[row * 256 + c];
            float4 sc0 = *(const float4*)&stats[c];
            float4 sc1 = *(const float4*)&stats[c + 4];
            float4 sh0 = *(const float4*)&stats[256 + c];
            float4 sh1 = *(const float4*)&stats[256 + c + 4];
            float scv[8] = {sc0.x, sc0.y, sc0.z, sc0.w, sc1.x, sc1.y, sc1.z, sc1.w};
            float shv[8] = {sh0.x, sh0.y, sh0.z, sh0.w, sh1.x, sh1.y, sh1.z, sh1.w};
            unsigned short* u = (unsigned short*)&av;
            const unsigned short* ru = (const unsigned short*)&rv;
#pragma unroll
            for (int j = 0; j < 8; ++j) {
                float v = fmaf(u2f(u[j]), scv[j], shv[j]);
                v = fmaxf(v, 0.f) + u2f(ru[j]);
                u[j] = f2u(fmaxf(v, 0.f));
            }
            if (Zout) *(s8*)&Zout[(long)g * 32768 + row * 256 + c] = av;
            *(s8*)&sStg[swz(row, sl)] = av;
            *(s8*)&sStg[8192 + swz(row, sl)] = *(const s8*)&W[(h * 128 + row) * 256 + c];
        }
        __syncthreads();
        mfma_s1(sStg, sStg + 8192, acc1, wm, wn, l15, kq);
    }
    tstore(sOut, acc1, wm, wn, l15, kq);
    __syncthreads();
    stageAdj(sStg, Adj, g, t);
    __syncthreads();
    f4 acc2[4][2] = {};
    mfma_s2(sStg, sOut, acc2, wm, wn, l15, kq);
    ag_part(acc2, AG, part, sStg, g, h, t, wm, wn, l15, kq, lane);
}

// layer-0 GCN half (K=128, bf16 x)
__device__ __forceinline__ void l0_gcn(const bf* Xg, const bf* W0, const bf* Adj,
                                       bf* AG, float* part, bf* sOut, bf* sStg,
                                       int g, int h, int t, int lane,
                                       int wm, int wn, int l15, int kq) {
    f4 acc1[4][2] = {};
    for (int k0 = 0; k0 < 128; k0 += 64) {
        __syncthreads();
#pragma unroll
        for (int i = 0; i < 2; ++i) {
            int sdx = i * 512 + t;
            int row = sdx >> 3, sl = sdx & 7;
            int c = k0 + sl * 8;
            *(s8*)&sStg[swz(row, sl)] = *(const s8*)&Xg[row * 128 + c];
            *(s8*)&sStg[8192 + swz(row, sl)] = *(const s8*)&W0[(h * 128 + row) * 128 + c];
        }
        __syncthreads();
        mfma_s1(sStg, sStg + 8192, acc1, wm, wn, l15, kq);
    }
    tstore(sOut, acc1, wm, wn, l15, kq);
    __syncthreads();
    stageAdj(sStg, Adj, g, t);
    __syncthreads();
    f4 acc2[4][2] = {};
    mfma_s2(sStg, sOut, acc2, wm, wn, l15, kq);
    ag_part(acc2, AG, part, sStg, g, h, t, wm, wn, l15, kq, lane);
}

// layer-0 shortcut half: ResOut = x @ scW^T + b
__device__ __forceinline__ void l0_sc(const bf* Xg, const bf* Wsc, const float* scb,
                                      bf* ResOut, bf* sStg, int g, int h, int t,
                                      int wm, int wn, int l15, int kq) {
    f4 acc1[4][2] = {};
    for (int k0 = 0; k0 < 128; k0 += 64) {
        __syncthreads();
#pragma unroll
        for (int i = 0; i < 2; ++i) {
            int sdx = i * 512 + t;
            int row = sdx >> 3, sl = sdx & 7;
            int c = k0 + sl * 8;
            *(s8*)&sStg[swz(row, sl)] = *(const s8*)&Xg[row * 128 + c];
            *(s8*)&sStg[8192 + swz(row, sl)] = *(const s8*)&Wsc[(h * 128 + row) * 128 + c];
        }
        __syncthreads();
        mfma_s1(sStg, sStg + 8192, acc1, wm, wn, l15, kq);
    }
#pragma unroll
    for (int fr = 0; fr < 4; ++fr) {
        int rl = wm * 64 + fr * 16 + kq * 4;
#pragma unroll
        for (int fc = 0; fc < 2; ++fc) {
            int cl = wn * 32 + fc * 16 + l15;
            float bv = scb[h * 128 + cl];
#pragma unroll
            for (int i = 0; i < 4; ++i)
                ResOut[(long)(g * 128 + rl + i) * 256 + h * 128 + cl] =
                    f2bf(acc1[fr][fc][i] + bv);
        }
    }
}

__device__ __forceinline__ void finz_inline(const bf* X, const float* stats,
                                            const bf* res, float* outz, bf* Znb,
                                            unsigned* zgu, float* pmLds,
                                            int g, int half, int t) {
    int lane = t & 63, w = t >> 6;
    int c4 = lane * 4;
    float4 sc = *(const float4*)&stats[c4];
    float4 sh = *(const float4*)&stats[256 + c4];
    float scv[4] = {sc.x, sc.y, sc.z, sc.w};
    float shv[4] = {sh.x, sh.y, sh.z, sh.w};
    float cmax[4] = {0.f, 0.f, 0.f, 0.f};
#pragma unroll
    for (int it = 0; it < 8; ++it) {
        int r = half * 64 + w * 8 + it;
        long i = (long)(g * 128 + r) * 256 + c4;
        ushort4 xv = *(const ushort4*)(X + i);
        ushort4 rv = *(const ushort4*)(res + i);
        unsigned short xs[4] = {xv.x, xv.y, xv.z, xv.w};
        unsigned short rs[4] = {rv.x, rv.y, rv.z, rv.w};
        float v[4];
        float s = 0.f;
#pragma unroll
        for (int j = 0; j < 4; ++j) {
            float vv = fmaf(u2f(xs[j]), scv[j], shv[j]);
            vv = fmaxf(vv, 0.f) + u2f(rs[j]);
            vv = fmaxf(vv, 0.f);
            v[j] = vv;
            s += vv * vv;
        }
#pragma unroll
        for (int o = 1; o < 64; o <<= 1) s += __shfl_xor(s, o);
        float den = fmaxf(sqrtf(s), 1e-12f);
        float4 fo;
        unsigned short us[4];
#pragma unroll
        for (int j = 0; j < 4; ++j) {
            float o = v[j] / den;
            ((float*)&fo)[j] = o;
            us[j] = f2u(o);
            cmax[j] = fmaxf(cmax[j], o);
        }
        *(float4*)(outz + i) = fo;
        *(ushort4*)(Znb + i) = make_ushort4(us[0], us[1], us[2], us[3]);
    }
    float (*pm)[256] = (float(*)[256])pmLds;
    __syncthreads();
#pragma unroll
    for (int j = 0; j < 4; ++j) pm[w][c4 + j] = cmax[j];
    __syncthreads();
    if (t < 256) {
        float m = pm[0][t];
#pragma unroll
        for (int ww = 1; ww < 8; ++ww) m = fmaxf(m, pm[ww][t]);
        atomicMax(&zgu[g * 256 + t], __float_as_uint(m));
    }
}

// ---------------- trunk kernels ----------------
__global__ __launch_bounds__(512) void k_l0(
    const bf* __restrict__ xb, const bf* __restrict__ W0, const bf* __restrict__ Wsc,
    const float* __restrict__ scb, const bf* __restrict__ Adj,
    bf* __restrict__ AG, bf* __restrict__ ResOut, float* __restrict__ part) {
    __shared__ __align__(16) bf sOut[16384];
    __shared__ __align__(16) bf sStg[16384];
    const int g = blockIdx.x, h = blockIdx.y;
    const int t = threadIdx.x;
    const int lane = t & 63, w = t >> 6;
    const int wm = w >> 2, wn = w & 3;
    const int l15 = lane & 15, kq = lane >> 4;
    const bf* Xg = xb + (long)g * 16384;
    if (h < 2)
        l0_gcn(Xg, W0, Adj, AG, part, sOut, sStg, g, h, t, lane, wm, wn, l15, kq);
    else
        l0_sc(Xg, Wsc, scb, ResOut, sStg, g, h - 2, t, wm, wn, l15, kq);
}

// GCN layer with in-kernel stats (reads partIn; writes partOut)
__global__ __launch_bounds__(512) void k_layer(
    const bf* __restrict__ Xin, const bf* __restrict__ Res,
    const float* __restrict__ partIn, const float* __restrict__ gam,
    const float* __restrict__ bet, const bf* __restrict__ Wt,
    const bf* __restrict__ Adj, bf* __restrict__ Zout, bf* __restrict__ AG,
    float* __restrict__ partOut) {
    __shared__ __align__(16) bf sOut[16384];
    __shared__ __align__(16) bf sStg[16384];
    const int g = blockIdx.x, h = blockIdx.y;
    const int t = threadIdx.x;
    const int lane = t & 63, w = t >> 6;
    const int wm = w >> 2, wn = w & 3;
    const int l15 = lane & 15, kq = lane >> 4;
    float* sS = (float*)sOut;   // stats live in sOut until tstore (safe: read-before-write)
    stats512(partIn, gam, bet, sS, t);
    gcn_layer(Xin + (long)g * 32768, Res + (long)g * 32768, sS, Wt, Adj,
              h == 0 ? Zout : nullptr, AG, partOut, sOut, sStg,
              g, h, t, lane, wm, wn, l15, kq);
}

__global__ __launch_bounds__(512) void k_finz(
    const bf* __restrict__ X, const float* __restrict__ partIn,
    const float* __restrict__ gam, const float* __restrict__ bet,
    const bf* __restrict__ res, float* __restrict__ outz, bf* __restrict__ Znb,
    unsigned* __restrict__ zgu) {
    __shared__ float sS[512];
    __shared__ float pm[8][256];
    stats512(partIn, gam, bet, sS, threadIdx.x);
    finz_inline(X, sS, res, outz, Znb, zgu, (float*)pm,
                blockIdx.x, blockIdx.y, threadIdx.x);
}

// ---------------- fd stage-1 layer (device fn, used by k_edfd) ----------------
__device__ __forceinline__ void fd_layer(const bf* Zg, const bf* W, const float* bias,
                                         bf* C, float* part, bf* sStg,
                                         int g, int h, int t, int lane,
                                         int wm, int wn, int l15, int kq) {
    f4 acc[4][2] = {};
    for (int k0 = 0; k0 < 256; k0 += 64) {
        __syncthreads();
#pragma unroll
        for (int i = 0; i < 2; ++i) {
            int sdx = i * 512 + t;
            int row = sdx >> 3, sl = sdx & 7;
            int c = k0 + sl * 8;
            *(s8*)&sStg[swz(row, sl)] = *(const s8*)&Zg[row * 256 + c];
            *(s8*)&sStg[8192 + swz(row, sl)] = *(const s8*)&W[(h * 128 + row) * 256 + c];
        }
        __syncthreads();
        mfma_s1(sStg, sStg + 8192, acc, wm, wn, l15, kq);
    }
    float ps[2] = {0.f, 0.f}, ps2[2] = {0.f, 0.f};
#pragma unroll
    for (int fr = 0; fr < 4; ++fr) {
        int rl = wm * 64 + fr * 16 + kq * 4;
#pragma unroll
        for (int fc = 0; fc < 2; ++fc) {
            int cl = wn * 32 + fc * 16 + l15;
            float bv = bias[h * 128 + cl];
#pragma unroll
            for (int i = 0; i < 4; ++i) {
                float v = fmaxf(acc[fr][fc][i] + bv, 0.f);
                ps[fc] += v; ps2[fc] += v * v;
                C[(long)(g * 128 + rl + i) * 256 + h * 128 + cl] = f2bf(v);
            }
        }
    }
    __syncthreads();
    float* scr = (float*)sStg;
#pragma unroll
    for (int fc = 0; fc < 2; ++fc) {
        ps[fc] += __shfl_xor(ps[fc], 16);  ps[fc] += __shfl_xor(ps[fc], 32);
        ps2[fc] += __shfl_xor(ps2[fc], 16); ps2[fc] += __shfl_xor(ps2[fc], 32);
    }
    if (lane < 16) {
#pragma unroll
        for (int fc = 0; fc < 2; ++fc) {
            int c = wn * 32 + fc * 16 + lane;
            scr[(c * 2 + wm) * 2 + 0] = ps[fc];
            scr[(c * 2 + wm) * 2 + 1] = ps2[fc];
        }
    }
    __syncthreads();
    if (t < 256) {
        int col = t & 127, s = t >> 7;
        part[(long)(h * 256 + g) * 256 + s * 128 + col] =
            scr[(col * 2 + 0) * 2 + s] + scr[(col * 2 + 1) * 2 + s];
    }
}

// ---------------- edge decoder + fd0 + ph0, one dispatch (772 blocks) ----------------
__global__ __launch_bounds__(512) void k_edfd(
    const bf* __restrict__ Zn, const bf* __restrict__ ewT,
    const bf* __restrict__ fdw, const float* __restrict__ fdb,
    const float* __restrict__ zgf, const bf* __restrict__ phw, 
    const float* __restrict__ phb,
    float* __restrict__ adjout, bf* __restrict__ C, float* __restrict__ part,
    bf* __restrict__ P1b) {
    __shared__ __align__(16) bf sOut[16384];
    __shared__ __align__(16) bf sStg[16384];
    const int t = threadIdx.x;
    const int lane = t & 63, w = t >> 6;
    const int wm = w >> 2, wn = w & 3;
    const int l15 = lane & 15, kq = lane >> 4;
    if (blockIdx.x >= 768) {
        // ---- ph0: P1 = relu(zg @ phw^T + phb), zg f32 [256][256] ----
        int bb = blockIdx.x - 768;
        int gz = bb & 1, h = bb >> 1;
        f4 acc[4][2] = {};
        for (int k0 = 0; k0 < 256; k0 += 64) {
            __syncthreads();
#pragma unroll
            for (int i = 0; i < 2; ++i) {
                int sdx = i * 512 + t;
                int row = sdx >> 3, sl = sdx & 7;
                int c = k0 + sl * 8;
                const float* src = zgf + (long)(gz * 128 + row) * 256 + c;
                float4 f0 = *(const float4*)src;
                float4 f1 = *(const float4*)(src + 4);
                unsigned short u[8] = {f2u(f0.x), f2u(f0.y), f2u(f0.z), f2u(f0.w),
                                       f2u(f1.x), f2u(f1.y), f2u(f1.z), f2u(f1.w)};
                *(s8*)&sStg[swz(row, sl)] = *(s8*)u;
                *(s8*)&sStg[8192 + swz(row, sl)] =
                    *(const s8*)&phw[(h * 128 + row) * 256 + c];
            }
            __syncthreads();
            mfma_s1(sStg, sStg + 8192, acc, wm, wn, l15, kq);
        }
#pragma unroll
        for (int fr = 0; fr < 4; ++fr) {
            int rl = wm * 64 + fr * 16 + kq * 4;
#pragma unroll
            for (int fc = 0; fc < 2; ++fc) {
                int cl = wn * 32 + fc * 16 + l15;
                float bv = phb[h * 128 + cl];
#pragma unroll
                for (int i = 0; i < 4; ++i)
                    P1b[(long)(gz * 128 + rl + i) * 256 + h * 128 + cl] =
                        f2bf(fmaxf(acc[fr][fc][i] + bv, 0.f));
            }
        }
        return;
    }
    if (blockIdx.x >= 256) {
        int bb = blockIdx.x - 256;
        int g = bb & 255, h = bb >> 8;
        fd_layer(Zn + (long)g * 32768, fdw, fdb, C, part, sStg,
                 g, h, t, lane, wm, wn, l15, kq);
        return;
    }
    const int g = blockIdx.x;
    const bf* Xg = Zn + (long)g * 32768;
    f4 acc2[4][2] = {};
    for (int h = 0; h < 2; ++h) {
        f4 acc1[4][2] = {};
        for (int k0 = 0; k0 < 256; k0 += 64) {
            __syncthreads();
#pragma unroll
            for (int i = 0; i < 2; ++i) {
                int sdx = i * 512 + t;
                int row = sdx >> 3, sl = sdx & 7;
                int c = k0 + sl * 8;
                *(s8*)&sStg[swz(row, sl)] = *(const s8*)&ewT[(h * 128 + row) * 256 + c];
                *(s8*)&sStg[8192 + swz(row, sl)] = *(const s8*)&Xg[row * 256 + c];
            }
            __syncthreads();
            mfma_s1(sStg, sStg + 8192, acc1, wm, wn, l15, kq);
        }
        tstore(sOut, acc1, wm, wn, l15, kq);
        __syncthreads();
#pragma unroll
        for (int i = 0; i < 4; ++i) {
            int sdx = i * 512 + t;
            int row = sdx >> 4, sl = sdx & 15;
            *(s8*)&sStg[swz128(row, sl)] = *(const s8*)&Xg[row * 256 + h * 128 + sl * 8];
        }
        __syncthreads();
        mfma_s2(sStg, sOut, acc2, wm, wn, l15, kq);
        __syncthreads();
    }
#pragma unroll
    for (int fr = 0; fr < 4; ++fr) {
        int rl = wm * 64 + fr * 16 + kq * 4;
#pragma unroll
        for (int fc = 0; fc < 2; ++fc) {
            int cl = wn * 32 + fc * 16 + l15;
            float vv[4];
#pragma unroll
            for (int i = 0; i < 4; ++i) {
                float v = 1.f / (1.f + __expf(-acc2[fr][fc][i]));
                if (cl == rl + i) v = 0.f;
                vv[i] = v;
            }
            float4 o; o.x = vv[0]; o.y = vv[1]; o.z = vv[2]; o.w = vv[3];
            *(float4*)&adjout[((long)g << 14) + cl * 128 + rl] = o;
        }
    }
}

// ---------------- MFMA GEMM (fd1/fd2/ph1) ----------------
// BNA: compute BN stats in-kernel from partIn (gam/bet) and apply to A on staging.
template <int EPI, int OUT, bool PART, bool BNA>
__global__ __launch_bounds__(256) void mg(
    const bf* __restrict__ A, const bf* __restrict__ BT,
    const float* __restrict__ bias, const float* __restrict__ partIn,
    const float* __restrict__ gam, const float* __restrict__ bet,
    float* __restrict__ Cf, bf* __restrict__ Cb, float* __restrict__ partOut,
    int M, int N, int K, int ldc) {
    __shared__ __align__(16) bf sAl[128 * 64];
    __shared__ __align__(16) bf sBl[128 * 64];
    __shared__ float sS[512];
    const int t = threadIdx.x;
    if (BNA) stats256(partIn, gam, bet, sS, t);
    const int m0 = blockIdx.y * 128, n0 = blockIdx.x * 128;
    const bf* Ab = A + (long)m0 * K;
    const bf* Bb = BT + (long)n0 * K;
    const int lane = t & 63;
    const int w = t >> 6;
    const int wm = (w >> 1) * 64, wn = (w & 1) * 64;
    const int fr16 = lane & 15, kq = lane >> 4;
    f4 acc[4][4] = {};
    for (int k0 = 0; k0 < K; k0 += 64) {
#pragma unroll
        for (int i = 0; i < 4; ++i) {
            int sdx = i * 256 + t;
            int row = sdx >> 3, sl = sdx & 7;
            s8 av = *(const s8*)&Ab[(long)row * K + k0 + sl * 8];
            if constexpr (BNA) {
                int c = k0 + sl * 8;
                float4 sc0 = *(const float4*)&sS[c];
                float4 sc1 = *(const float4*)&sS[c + 4];
                float4 sh0 = *(const float4*)&sS[256 + c];
                float4 sh1 = *(const float4*)&sS[256 + c + 4];
                float scv[8] = {sc0.x, sc0.y, sc0.z, sc0.w, sc1.x, sc1.y, sc1.z, sc1.w};
                float shv[8] = {sh0.x, sh0.y, sh0.z, sh0.w, sh1.x, sh1.y, sh1.z, sh1.w};
                unsigned short* u = (unsigned short*)&av;
#pragma unroll
                for (int j = 0; j < 8; ++j)
                    u[j] = f2u(fmaf(u2f(u[j]), scv[j], shv[j]));
            }
            *(s8*)&sAl[swz(row, sl)] = av;
            *(s8*)&sBl[swz(row, sl)] = *(const s8*)&Bb[(long)row * K + k0 + sl * 8];
        }
        __syncthreads();
#pragma unroll
        for (int ks = 0; ks < 2; ++ks) {
            s8 af[4], bg[4];
#pragma unroll
            for (int f = 0; f < 4; ++f) {
                af[f] = *(const s8*)&sAl[swz(wm + f * 16 + fr16, kq + 4 * ks)];
                bg[f] = *(const s8*)&sBl[swz(wn + f * 16 + fr16, kq + 4 * ks)];
            }
#pragma unroll
            for (int fr = 0; fr < 4; ++fr)
#pragma unroll
                for (int fc = 0; fc < 4; ++fc)
                    acc[fr][fc] = __builtin_amdgcn_mfma_f32_16x16x32_bf16(
                        af[fr], bg[fc], acc[fr][fc], 0, 0, 0);
        }
        __syncthreads();
    }
    float ps[4], ps2[4];
    if (PART) {
#pragma unroll
        for (int fc = 0; fc < 4; ++fc) { ps[fc] = 0.f; ps2[fc] = 0.f; }
    }
#pragma unroll
    for (int fr = 0; fr < 4; ++fr) {
        int rl = wm + fr * 16 + (lane >> 4) * 4;
#pragma unroll
        for (int fc = 0; fc < 4; ++fc) {
            int cl = wn + fc * 16 + (lane & 15);
            int col = n0 + cl;
            float bv = bias[col];
#pragma unroll
            for (int i = 0; i < 4; ++i) {
                float v = acc[fr][fc][i] + bv;
                if (EPI == 2) v = fmaxf(v, 0.f);
                if (PART) { ps[fc] += v; ps2[fc] += v * v; }
                if (OUT == 0) Cf[(long)(m0 + rl + i) * ldc + col] = v;
                if (OUT == 1) Cb[(long)(m0 + rl + i) * ldc + col] = f2bf(v);
            }
        }
    }
    if (PART) {
        __syncthreads();
        float* scr = (float*)sAl;
#pragma unroll
        for (int fc = 0; fc < 4; ++fc) {
            ps[fc] += __shfl_xor(ps[fc], 16);  ps[fc] += __shfl_xor(ps[fc], 32);
            ps2[fc] += __shfl_xor(ps2[fc], 16); ps2[fc] += __shfl_xor(ps2[fc], 32);
        }
        if (lane < 16) {
#pragma unroll
            for (int fc = 0; fc < 4; ++fc) {
                scr[(w * 2 + 0) * 64 + fc * 16 + lane] = ps[fc];
                scr[(w * 2 + 1) * 64 + fc * 16 + lane] = ps2[fc];
            }
        }
        __syncthreads();
        int id = blockIdx.x * gridDim.y + blockIdx.y;   // gridDim = (2, 256)
        int stat = t >> 7, c = t & 127;
        int ci = c & 63, half = c >> 6;
        float v = scr[(half * 2 + stat) * 64 + ci] + scr[((half + 2) * 2 + stat) * 64 + ci];
        partOut[(long)id * 256 + stat * 128 + c] = v;
    }
}

// ---------------- host ----------------
extern "C" void kernel_launch(void* const* d_in, const int* in_sizes, int n_in,
                              void* d_out, int out_size, void* d_ws, size_t ws_size,
                              hipStream_t stream) {
    const float* x      = (const float*)d_in[0];
    const int*   srcL   = (const int*)d_in[1];
    const int*   dstL   = (const int*)d_in[2];
    const float* gcn_w0 = (const float*)d_in[3];
    const float* bn_g0  = (const float*)d_in[5];
    const float* bn_b0  = (const float*)d_in[6];
    const float* gcn_w1 = (const float*)d_in[7];
    const float* bn_g1  = (const float*)d_in[9];
    const float* bn_b1  = (const float*)d_in[10];
    const float* gcn_w2 = (const float*)d_in[11];
    const float* bn_g2  = (const float*)d_in[13];
    const float* bn_b2  = (const float*)d_in[14];
    const float* sc_w0  = (const float*)d_in[15];
    const float* sc_b0  = (const float*)d_in[16];
    const float* edge_w = (const float*)d_in[17];
    const float* fd_w0  = (const float*)d_in[18];
    const float* fd_b0  = (const float*)d_in[19];
    const float* fd_g0  = (const float*)d_in[20];
    const float* fd_be0 = (const float*)d_in[21];
    const float* fd_w1  = (const float*)d_in[22];
    const float* fd_b1  = (const float*)d_in[23];
    const float* fd_g1  = (const float*)d_in[24];
    const float* fd_be1 = (const float*)d_in[25];
    const float* fd_w2  = (const float*)d_in[26];
    const float* fd_b2  = (const float*)d_in[27];
    const float* ph_w0  = (const float*)d_in[28];
    const float* ph_b0  = (const float*)d_in[29];
    const float* ph_w1  = (const float*)d_in[30];
    const float* ph_b1  = (const float*)d_in[31];

    float* out     = (float*)d_out;
    float* out_z   = out;
    float* out_adj = out + 8388608;
    float* out_xr  = out + 12582912;
    float* out_zg  = out + 16777216;
    float* out_zgm = out + 16842752;

    float* w      = (float*)d_ws;
    float* partA  = w;                        // 131072
    float* partB  = w + 131072;               // 131072
    bf*    wT     = (bf*)(w + 262144);        // 557056 bf16 = 278528 f
    bf*    Aadjb  = (bf*)(w + 540672);        // 4194304 bf16 = 2097152 f
    bf*    U4     = (bf*)(w + 2637824);       // 8388608 bf16 = 4194304 f
    bf*    U1     = (bf*)(w + 6832128);
    bf*    U2     = (bf*)(w + 11026432);
    bf*    U3     = (bf*)(w + 15220736);
    bf*    P1b    = (bf*)(w + 19415040);      // 65536 bf16
    bf*    xb     = (bf*)(w + 19447808);      // 4194304 bf16
    // total ~86.2 MB

    WTpack pk;
    pk.w[0] = {gcn_w0, 128, 256, 0};
    pk.w[1] = {sc_w0,  128, 256, 32768};
    pk.w[2] = {gcn_w1, 256, 256, 65536};
    pk.w[3] = {gcn_w2, 256, 256, 131072};
    pk.w[4] = {edge_w, 256, 256, 196608};
    pk.w[5] = {fd_w0,  256, 256, 262144};
    pk.w[6] = {fd_w1,  256, 256, 327680};
    pk.w[7] = {fd_w2,  256, 128, 393216};
    pk.w[8] = {ph_w0,  256, 256, 425984};
    pk.w[9] = {ph_w1,  256, 256, 491520};

    // zero out_zg early (atomicMax target; harness poisons d_out)
    hipMemsetAsync(out_zg, 0, 65536 * 4, stream);

    // --- prep: adjacency + weight transpose + x->bf16 ---
    k_prep<<<672, 256, 0, stream>>>(srcL, dstL, x, pk, Aadjb, xb, wT);

    // --- trunk (BN finalize folded into consumers) ---
    k_l0<<<dim3(256, 4), 512, 0, stream>>>(xb, wT, wT + 32768, sc_b0, Aadjb,
                                           U2, U1, partA);
    k_layer<<<dim3(256, 2), 512, 0, stream>>>(U2, U1, partA, bn_g0, bn_b0,
                                              wT + 65536, Aadjb, U3, U4, partB);
    k_layer<<<dim3(256, 2), 512, 0, stream>>>(U4, U3, partB, bn_g1, bn_b1,
                                              wT + 131072, Aadjb, U1, U2, partA);
    k_finz<<<dim3(256, 2), 512, 0, stream>>>(U2, partA, bn_g2, bn_b2, U1,
                                             out_z, U3, (unsigned*)out_zg);

    // --- edge decoder + fd0 + ph0, one dispatch ---
    k_edfd<<<772, 512, 0, stream>>>(U3, wT + 196608, wT + 262144, fd_b0,
                                    out_zg, wT + 425984, ph_b0,
                                    out_adj, U4, partB, P1b);

    // --- feature decoder (fd1 w/ fd0-stats, fd2 w/ fd1-stats) ---
    mg<2, 1, true, true><<<dim3(2, 256), 256, 0, stream>>>(
        U4, wT + 327680, fd_b1, partB, fd_g0, fd_be0,
        nullptr, U2, partA, NN, HD, HD, 256);
    mg<1, 0, false, true><<<dim3(1, 256), 256, 0, stream>>>(
        U2, wT + 393216, fd_b2, partA, fd_g1, fd_be1,
        out_xr, nullptr, nullptr, NN, 128, HD, 128);

    // --- pooling head tail (ph1) ---
    mg<1, 0, false, false><<<dim3(2, 2), 256, 0, stream>>>(
        P1b, wT + 491520, ph_b1, nullptr, nullptr, nullptr,
        out_zgm, nullptr, nullptr, 256, 256, 256, 256);
}

// Round 16
// 177.911 us; speedup vs baseline: 3.2915x; 1.1312x over previous
//
#include <hip/hip_runtime.h>
#include <hip/hip_bf16.h>

using bf = __hip_bfloat16;
typedef __attribute__((ext_vector_type(8))) short s8;
typedef __attribute__((ext_vector_type(4))) float f4;

constexpr int NN  = 32768;
constexpr int HD  = 256;

__device__ __forceinline__ float u2f(unsigned short h) {
    union { unsigned u; float f; } x; x.u = ((unsigned)h) << 16;
    return x.f;
}
__device__ __forceinline__ unsigned short f2u(float f) {
    union { float f; unsigned u; } x; x.f = f;
    unsigned r = x.u + 0x7FFF + ((x.u >> 16) & 1);
    return (unsigned short)(r >> 16);
}
__device__ __forceinline__ bf f2bf(float f) {
    unsigned short h = f2u(f);
    return *reinterpret_cast<bf*>(&h);
}
__device__ __forceinline__ float bf2f(bf b) {
    return u2f(*reinterpret_cast<unsigned short*>(&b));
}

__device__ __forceinline__ int swz(int row, int slot) {      // 64-col rows
    return row * 64 + ((slot ^ (row & 7)) << 3);
}
__device__ __forceinline__ int swz128(int row, int slot) {   // 128-col rows
    return row * 128 + ((slot ^ (row & 7)) << 3);
}

// async global->LDS, 16B per lane; LDS dest = wave-uniform base + lane*16.
typedef const __attribute__((address_space(1))) unsigned int guint;
typedef __attribute__((address_space(3))) unsigned int luint;
__device__ __forceinline__ void gload16(const void* g, void* l) {
    __builtin_amdgcn_global_load_lds((guint*)g, (luint*)l, 16, 0, 0);
}

// ---------------- prep: adjacency + weight transpose + x cvt, one dispatch ----
struct WTd { const float* src; int K, N, off; };
struct WTpack { WTd w[10]; };

__global__ __launch_bounds__(256) void k_prep(const int* __restrict__ srcL,
                                              const int* __restrict__ dstL,
                                              const float* __restrict__ xf,
                                              WTpack p, bf* __restrict__ A,
                                              bf* __restrict__ xb,
                                              bf* __restrict__ wT) {
    __shared__ __align__(16) float shm[8320];
    int b = blockIdx.x, t = threadIdx.x;
    if (b < 256) {
        float* sT = shm;
        float* sdin = shm + 8192;
        int g = b;
        const int* sg = srcL + (g << 11);
        const int* dg = dstL + (g << 11);
        if (t < 128) sdin[t] = 0.f;
        __syncthreads();
        for (int e = t; e < 2048; e += 256) atomicAdd(&sdin[dg[e]], 1.0f);
        __syncthreads();
        if (t < 128) sdin[t] = rsqrtf(sdin[t] + 1.0f);
        __syncthreads();
        bf* out = A + ((long)g << 14);
        for (int half = 0; half < 2; ++half) {
            for (int i = t; i < 8192; i += 256) sT[i] = 0.f;
            __syncthreads();
            for (int e = t; e < 2048; e += 256) {
                int s = sg[e], d = dg[e];
                if ((s >> 6) == half)
                    atomicAdd(&sT[(d << 6) + (s & 63)], sdin[s] * sdin[d]);
            }
            __syncthreads();
            if (t < 128 && (t >> 6) == half)
                sT[(t << 6) + (t & 63)] += sdin[t] * sdin[t];
            __syncthreads();
            for (int i4 = t; i4 < 2048; i4 += 256) {
                int d = i4 >> 4, c4 = (i4 & 15) * 4;
                float4 v = *(float4*)&sT[(d << 6) + c4];
                ushort4 u = make_ushort4(f2u(v.x), f2u(v.y), f2u(v.z), f2u(v.w));
                *(ushort4*)&out[(d << 7) + (half << 6) + c4] = u;
            }
            __syncthreads();
        }
    } else if (b < 416) {
        int idx = b - 256;
        WTd d = p.w[idx >> 4];
        int rem = idx & 15;
        int n0 = (rem & 3) * 64, k0 = (rem >> 2) * 64;
        if (n0 >= d.N || k0 >= d.K) return;
        float (*s)[65] = (float(*)[65])shm;
        int cc = t & 63, rq = t >> 6;
#pragma unroll
        for (int i = 0; i < 16; ++i) {
            int r = i * 4 + rq;
            s[r][cc] = d.src[(long)(k0 + r) * d.N + n0 + cc];
        }
        __syncthreads();
#pragma unroll
        for (int i = 0; i < 16; ++i) {
            int r = i * 4 + rq;
            wT[d.off + (long)(n0 + r) * d.K + k0 + cc] = f2bf(s[cc][r]);
        }
    } else {
        long base = (long)(b - 416) * 16384;
#pragma unroll
        for (int it = 0; it < 16; ++it) {
            long i4 = base + (it * 256 + t) * 4;
            float4 v = *(const float4*)&xf[i4];
            *(ushort4*)&xb[i4] = make_ushort4(f2u(v.x), f2u(v.y), f2u(v.z), f2u(v.w));
        }
    }
}

// ---------------- MFMA helpers (512-thr per-graph kernels) ----------------
__device__ __forceinline__ void mfma_s1(const bf* sA, const bf* sB, f4 (&acc)[4][2],
                                        int wm, int wn, int l15, int kq) {
#pragma unroll
    for (int ks = 0; ks < 2; ++ks) {
        s8 af[4], bg[2];
#pragma unroll
        for (int f = 0; f < 4; ++f)
            af[f] = *(const s8*)&sA[swz(wm * 64 + f * 16 + l15, kq + 4 * ks)];
#pragma unroll
        for (int f = 0; f < 2; ++f)
            bg[f] = *(const s8*)&sB[swz(wn * 32 + f * 16 + l15, kq + 4 * ks)];
#pragma unroll
        for (int fr = 0; fr < 4; ++fr)
#pragma unroll
            for (int fc = 0; fc < 2; ++fc)
                acc[fr][fc] = __builtin_amdgcn_mfma_f32_16x16x32_bf16(
                    af[fr], bg[fc], acc[fr][fc], 0, 0, 0);
    }
}

__device__ __forceinline__ void mfma_s2(const bf* sA, const bf* sB, f4 (&acc)[4][2],
                                        int wm, int wn, int l15, int kq) {
#pragma unroll
    for (int ks = 0; ks < 4; ++ks) {
        s8 af[4], bg[2];
#pragma unroll
        for (int f = 0; f < 4; ++f)
            af[f] = *(const s8*)&sA[swz128(wm * 64 + f * 16 + l15, ks * 4 + kq)];
#pragma unroll
        for (int f = 0; f < 2; ++f)
            bg[f] = *(const s8*)&sB[swz128(wn * 32 + f * 16 + l15, ks * 4 + kq)];
#pragma unroll
        for (int fr = 0; fr < 4; ++fr)
#pragma unroll
            for (int fc = 0; fc < 2; ++fc)
                acc[fr][fc] = __builtin_amdgcn_mfma_f32_16x16x32_bf16(
                    af[fr], bg[fc], acc[fr][fc], 0, 0, 0);
    }
}

__device__ __forceinline__ void tstore(bf* sOut, f4 (&acc)[4][2],
                                       int wm, int wn, int l15, int kq) {
#pragma unroll
    for (int fr = 0; fr < 4; ++fr) {
        int rl = wm * 64 + fr * 16 + kq * 4;
#pragma unroll
        for (int fc = 0; fc < 2; ++fc) {
            int cl = wn * 32 + fc * 16 + l15;
            ushort4 q = make_ushort4(f2u(acc[fr][fc][0]), f2u(acc[fr][fc][1]),
                                     f2u(acc[fr][fc][2]), f2u(acc[fr][fc][3]));
            int off = cl * 128 + (((rl >> 3) ^ (cl & 7)) << 3) + (rl & 7);
            *(ushort4*)&sOut[off] = q;
        }
    }
}

// ---------------- fused per-graph kernels ----------------
// MODE 0 (grid 256x2): GCN layer, phase hb = blockIdx.y (independent col-halves)
// MODE 2 (grid 256x4): layer 0; phases 0,1 = GCN halves; 2,3 = shortcut halves
template <int MODE>
__global__ __launch_bounds__(512) void k_fused(
    const bf* __restrict__ Xin,
    const bf* __restrict__ Res, const float* __restrict__ stats,
    const bf* __restrict__ Wt, const bf* __restrict__ Wt2,
    const float* __restrict__ scb, const bf* __restrict__ Adj,
    bf* __restrict__ Zout, bf* __restrict__ AG, bf* __restrict__ ResOut,
    float* __restrict__ part) {
    __shared__ __align__(16) bf sOut[16384];
    __shared__ __align__(16) bf sStg[16384];
    const int g = blockIdx.x;
    const int h = blockIdx.y;
    const int t = threadIdx.x;
    const int lane = t & 63, w = t >> 6;
    const int wm = w >> 2, wn = w & 3;
    const int l15 = lane & 15, kq = lane >> 4;
    constexpr int KS1 = (MODE == 2) ? 128 : 256;
    const bf* Xg = Xin + (long)g * ((MODE == 2) ? 16384 : 32768);
    const bf* Rg = (MODE == 0) ? Res + (long)g * 32768 : nullptr;

    // ---- stage 1 ----
    f4 acc1[4][2] = {};
    for (int k0 = 0; k0 < KS1; k0 += 64) {
        __syncthreads();
#pragma unroll
        for (int i = 0; i < 2; ++i) {
            // A operand
            if constexpr (MODE == 0) {
                int sdx = i * 512 + t;
                int row = sdx >> 3, sl = sdx & 7;
                int c = k0 + sl * 8;
                s8 av = *(const s8*)&Xg[row * 256 + c];
                s8 rv = *(const s8*)&Rg[row * 256 + c];
                float4 sc0 = *(const float4*)&stats[c];
                float4 sc1 = *(const float4*)&stats[c + 4];
                float4 sh0 = *(const float4*)&stats[256 + c];
                float4 sh1 = *(const float4*)&stats[256 + c + 4];
                float scv[8] = {sc0.x, sc0.y, sc0.z, sc0.w, sc1.x, sc1.y, sc1.z, sc1.w};
                float shv[8] = {sh0.x, sh0.y, sh0.z, sh0.w, sh1.x, sh1.y, sh1.z, sh1.w};
                unsigned short* u = (unsigned short*)&av;
                const unsigned short* ru = (const unsigned short*)&rv;
#pragma unroll
                for (int j = 0; j < 8; ++j) {
                    float v = fmaf(u2f(u[j]), scv[j], shv[j]);
                    v = fmaxf(v, 0.f) + u2f(ru[j]);
                    u[j] = f2u(fmaxf(v, 0.f));
                }
                if (h == 0)
                    *(s8*)&Zout[(long)g * 32768 + row * 256 + c] = av;
                *(s8*)&sStg[swz(row, sl)] = av;
            } else {
                int r0 = i * 64 + 8 * w;
                int rw = r0 + (lane >> 3);
                int ps = ((lane & 7) ^ (rw & 7)) << 3;
                gload16(&Xg[rw * 128 + k0 + ps], &sStg[r0 * 64]);
            }
            // B operand (pre-swizzled source, linear LDS dest)
            {
                int r0 = i * 64 + 8 * w;
                int rw = r0 + (lane >> 3);
                int ps = ((lane & 7) ^ (rw & 7)) << 3;
                const bf* bsrc;
                if constexpr (MODE == 0)
                    bsrc = &Wt[(h * 128 + rw) * 256 + k0 + ps];
                else {
                    const bf* Wsrc = (h < 2) ? Wt : Wt2;
                    bsrc = &Wsrc[((h & 1) * 128 + rw) * 128 + k0 + ps];
                }
                gload16(bsrc, &sStg[8192 + r0 * 64]);
            }
        }
        __syncthreads();
        mfma_s1(sStg, sStg + 8192, acc1, wm, wn, l15, kq);
    }
    if (MODE == 2 && h >= 2) {
        // shortcut: direct row-major write + bias
#pragma unroll
        for (int fr = 0; fr < 4; ++fr) {
            int rl = wm * 64 + fr * 16 + kq * 4;
#pragma unroll
            for (int fc = 0; fc < 2; ++fc) {
                int cl = wn * 32 + fc * 16 + l15;
                float bv = scb[(h - 2) * 128 + cl];
#pragma unroll
                for (int i = 0; i < 4; ++i)
                    ResOut[(long)(g * 128 + rl + i) * 256 + (h - 2) * 128 + cl] =
                        f2bf(acc1[fr][fc][i] + bv);
            }
        }
        return;
    }
    // ---- transposed store + stage 2 ----
    tstore(sOut, acc1, wm, wn, l15, kq);
    __syncthreads();
#pragma unroll
    for (int i = 0; i < 4; ++i) {
        int r0 = i * 32 + 4 * w;
        int rw = r0 + (lane >> 4);
        int ps = ((lane & 15) ^ (rw & 7)) << 3;
        gload16(&Adj[((long)g << 14) + rw * 128 + ps], &sStg[r0 * 128]);
    }
    __syncthreads();
    f4 acc2[4][2] = {};
    mfma_s2(sStg, sOut, acc2, wm, wn, l15, kq);
    // ---- AG write + BN partials ----
    float ps[2] = {0.f, 0.f}, ps2[2] = {0.f, 0.f};
#pragma unroll
    for (int fr = 0; fr < 4; ++fr) {
        int rl = wm * 64 + fr * 16 + kq * 4;
#pragma unroll
        for (int fc = 0; fc < 2; ++fc) {
            int cl = wn * 32 + fc * 16 + l15;
#pragma unroll
            for (int i = 0; i < 4; ++i) {
                float v = acc2[fr][fc][i];
                ps[fc] += v; ps2[fc] += v * v;
                AG[(long)(g * 128 + rl + i) * 256 + (h & 1) * 128 + cl] = f2bf(v);
            }
        }
    }
    __syncthreads();
    float* scr = (float*)sStg;
#pragma unroll
    for (int fc = 0; fc < 2; ++fc) {
        ps[fc] += __shfl_xor(ps[fc], 16);  ps[fc] += __shfl_xor(ps[fc], 32);
        ps2[fc] += __shfl_xor(ps2[fc], 16); ps2[fc] += __shfl_xor(ps2[fc], 32);
    }
    if (lane < 16) {
#pragma unroll
        for (int fc = 0; fc < 2; ++fc) {
            int c = wn * 32 + fc * 16 + lane;
            scr[(c * 2 + wm) * 2 + 0] = ps[fc];
            scr[(c * 2 + wm) * 2 + 1] = ps2[fc];
        }
    }
    __syncthreads();
    if (t < 256) {
        int col = t & 127, s = t >> 7;
        part[(long)((h & 1) * 256 + g) * 256 + s * 128 + col] =
            scr[(col * 2 + 0) * 2 + s] + scr[(col * 2 + 1) * 2 + s];
    }
}

// ---------------- fd stage-1 layer (device fn, used by k_edfd) ----------------
__device__ __forceinline__ void fd_layer(const bf* Zg, const bf* W, const float* bias,
                                         bf* C, float* part, bf* sStg,
                                         int g, int h, int t, int lane,
                                         int wm, int wn, int l15, int kq) {
    f4 acc[4][2] = {};
    for (int k0 = 0; k0 < 256; k0 += 64) {
        __syncthreads();
#pragma unroll
        for (int i = 0; i < 2; ++i) {
            int sdx = i * 512 + t;
            int row = sdx >> 3, sl = sdx & 7;
            int c = k0 + sl * 8;
            *(s8*)&sStg[swz(row, sl)] = *(const s8*)&Zg[row * 256 + c];
            *(s8*)&sStg[8192 + swz(row, sl)] = *(const s8*)&W[(h * 128 + row) * 256 + c];
        }
        __syncthreads();
        mfma_s1(sStg, sStg + 8192, acc, wm, wn, l15, kq);
    }
    float ps[2] = {0.f, 0.f}, ps2[2] = {0.f, 0.f};
#pragma unroll
    for (int fr = 0; fr < 4; ++fr) {
        int rl = wm * 64 + fr * 16 + kq * 4;
#pragma unroll
        for (int fc = 0; fc < 2; ++fc) {
            int cl = wn * 32 + fc * 16 + l15;
            float bv = bias[h * 128 + cl];
#pragma unroll
            for (int i = 0; i < 4; ++i) {
                float v = fmaxf(acc[fr][fc][i] + bv, 0.f);
                ps[fc] += v; ps2[fc] += v * v;
                C[(long)(g * 128 + rl + i) * 256 + h * 128 + cl] = f2bf(v);
            }
        }
    }
    __syncthreads();
    float* scr = (float*)sStg;
#pragma unroll
    for (int fc = 0; fc < 2; ++fc) {
        ps[fc] += __shfl_xor(ps[fc], 16);  ps[fc] += __shfl_xor(ps[fc], 32);
        ps2[fc] += __shfl_xor(ps2[fc], 16); ps2[fc] += __shfl_xor(ps2[fc], 32);
    }
    if (lane < 16) {
#pragma unroll
        for (int fc = 0; fc < 2; ++fc) {
            int c = wn * 32 + fc * 16 + lane;
            scr[(c * 2 + wm) * 2 + 0] = ps[fc];
            scr[(c * 2 + wm) * 2 + 1] = ps2[fc];
        }
    }
    __syncthreads();
    if (t < 256) {
        int col = t & 127, s = t >> 7;
        part[(long)(h * 256 + g) * 256 + s * 128 + col] =
            scr[(col * 2 + 0) * 2 + s] + scr[(col * 2 + 1) * 2 + s];
    }
}

// ---------------- edge decoder + fd0 + ph0, one dispatch (772 blocks) ----------------
__global__ __launch_bounds__(512) void k_edfd(
    const bf* __restrict__ Zn, const bf* __restrict__ ewT,
    const bf* __restrict__ fdw, const float* __restrict__ fdb,
    const float* __restrict__ zgf, const bf* __restrict__ phw,
    const float* __restrict__ phb,
    float* __restrict__ adjout, bf* __restrict__ C, float* __restrict__ part,
    bf* __restrict__ P1b) {
    __shared__ __align__(16) bf sOut[16384];
    __shared__ __align__(16) bf sStg[16384];
    const int t = threadIdx.x;
    const int lane = t & 63, w = t >> 6;
    const int wm = w >> 2, wn = w & 3;
    const int l15 = lane & 15, kq = lane >> 4;
    if (blockIdx.x >= 768) {
        // ---- ph0: P1 = relu(zg @ phw^T + phb), zg f32 [256][256] ----
        int bb = blockIdx.x - 768;
        int gz = bb & 1, h = bb >> 1;
        f4 acc[4][2] = {};
        for (int k0 = 0; k0 < 256; k0 += 64) {
            __syncthreads();
#pragma unroll
            for (int i = 0; i < 2; ++i) {
                int sdx = i * 512 + t;
                int row = sdx >> 3, sl = sdx & 7;
                int c = k0 + sl * 8;
                const float* src = zgf + (long)(gz * 128 + row) * 256 + c;
                float4 f0 = *(const float4*)src;
                float4 f1 = *(const float4*)(src + 4);
                unsigned short u[8] = {f2u(f0.x), f2u(f0.y), f2u(f0.z), f2u(f0.w),
                                       f2u(f1.x), f2u(f1.y), f2u(f1.z), f2u(f1.w)};
                *(s8*)&sStg[swz(row, sl)] = *(s8*)u;
                *(s8*)&sStg[8192 + swz(row, sl)] =
                    *(const s8*)&phw[(h * 128 + row) * 256 + c];
            }
            __syncthreads();
            mfma_s1(sStg, sStg + 8192, acc, wm, wn, l15, kq);
        }
#pragma unroll
        for (int fr = 0; fr < 4; ++fr) {
            int rl = wm * 64 + fr * 16 + kq * 4;
#pragma unroll
            for (int fc = 0; fc < 2; ++fc) {
                int cl = wn * 32 + fc * 16 + l15;
                float bv = phb[h * 128 + cl];
#pragma unroll
                for (int i = 0; i < 4; ++i)
                    P1b[(long)(gz * 128 + rl + i) * 256 + h * 128 + cl] =
                        f2bf(fmaxf(acc[fr][fc][i] + bv, 0.f));
            }
        }
        return;
    }
    if (blockIdx.x >= 256) {
        int bb = blockIdx.x - 256;
        int g = bb & 255, h = bb >> 8;
        fd_layer(Zn + (long)g * 32768, fdw, fdb, C, part, sStg,
                 g, h, t, lane, wm, wn, l15, kq);
        return;
    }
    const int g = blockIdx.x;
    const bf* Xg = Zn + (long)g * 32768;
    f4 acc2[4][2] = {};
    for (int h = 0; h < 2; ++h) {
        f4 acc1[4][2] = {};
        for (int k0 = 0; k0 < 256; k0 += 64) {
            __syncthreads();
#pragma unroll
            for (int i = 0; i < 2; ++i) {
                int sdx = i * 512 + t;
                int row = sdx >> 3, sl = sdx & 7;
                int c = k0 + sl * 8;
                *(s8*)&sStg[swz(row, sl)] = *(const s8*)&ewT[(h * 128 + row) * 256 + c];
                *(s8*)&sStg[8192 + swz(row, sl)] = *(const s8*)&Xg[row * 256 + c];
            }
            __syncthreads();
            mfma_s1(sStg, sStg + 8192, acc1, wm, wn, l15, kq);
        }
        tstore(sOut, acc1, wm, wn, l15, kq);
        __syncthreads();
#pragma unroll
        for (int i = 0; i < 4; ++i) {
            int sdx = i * 512 + t;
            int row = sdx >> 4, sl = sdx & 15;
            *(s8*)&sStg[swz128(row, sl)] = *(const s8*)&Xg[row * 256 + h * 128 + sl * 8];
        }
        __syncthreads();
        mfma_s2(sStg, sOut, acc2, wm, wn, l15, kq);
        __syncthreads();
    }
#pragma unroll
    for (int fr = 0; fr < 4; ++fr) {
        int rl = wm * 64 + fr * 16 + kq * 4;
#pragma unroll
        for (int fc = 0; fc < 2; ++fc) {
            int cl = wn * 32 + fc * 16 + l15;
            float vv[4];
#pragma unroll
            for (int i = 0; i < 4; ++i) {
                float v = 1.f / (1.f + __expf(-acc2[fr][fc][i]));
                if (cl == rl + i) v = 0.f;
                vv[i] = v;
            }
            float4 o; o.x = vv[0]; o.y = vv[1]; o.z = vv[2]; o.w = vv[3];
            *(float4*)&adjout[((long)g << 14) + cl * 128 + rl] = o;
        }
    }
}

// ---------------- MFMA GEMM (fd1/fd2/ph1) ----------------
template <int EPI, int OUT, bool PART, bool BNA, bool AF32>
__global__ __launch_bounds__(256) void mg(
    const void* __restrict__ Av, const bf* __restrict__ BT,
    const float* __restrict__ bias, const float* __restrict__ bnstats,
    float* __restrict__ Cf, bf* __restrict__ Cb, float* __restrict__ part,
    int M, int N, int K, int ldc) {
    __shared__ __align__(16) bf sAl[128 * 64];
    __shared__ __align__(16) bf sBl[128 * 64];
    const int m0 = blockIdx.y * 128, n0 = blockIdx.x * 128;
    const bf* Bb = BT + (long)n0 * K;
    const int t = threadIdx.x;
    const int lane = t & 63;
    const int w = t >> 6;
    const int wm = (w >> 1) * 64, wn = (w & 1) * 64;
    const int fr16 = lane & 15, kq = lane >> 4;
    f4 acc[4][4] = {};
    for (int k0 = 0; k0 < K; k0 += 64) {
#pragma unroll
        for (int i = 0; i < 4; ++i) {
            int sdx = i * 256 + t;
            int row = sdx >> 3, sl = sdx & 7;
            s8 av;
            if constexpr (AF32) {
                const float* src = (const float*)Av + (long)(m0 + row) * K + k0 + sl * 8;
                float4 f0 = *(const float4*)src;
                float4 f1 = *(const float4*)(src + 4);
                unsigned short u[8] = {f2u(f0.x), f2u(f0.y), f2u(f0.z), f2u(f0.w),
                                       f2u(f1.x), f2u(f1.y), f2u(f1.z), f2u(f1.w)};
                av = *(s8*)u;
            } else {
                av = *(const s8*)&((const bf*)Av)[(long)(m0 + row) * K + k0 + sl * 8];
                if constexpr (BNA) {
                    int c = k0 + sl * 8;
                    float4 sc0 = *(const float4*)&bnstats[c];
                    float4 sc1 = *(const float4*)&bnstats[c + 4];
                    float4 sh0 = *(const float4*)&bnstats[256 + c];
                    float4 sh1 = *(const float4*)&bnstats[256 + c + 4];
                    float scv[8] = {sc0.x, sc0.y, sc0.z, sc0.w, sc1.x, sc1.y, sc1.z, sc1.w};
                    float shv[8] = {sh0.x, sh0.y, sh0.z, sh0.w, sh1.x, sh1.y, sh1.z, sh1.w};
                    unsigned short* u = (unsigned short*)&av;
#pragma unroll
                    for (int j = 0; j < 8; ++j)
                        u[j] = f2u(fmaf(u2f(u[j]), scv[j], shv[j]));
                }
            }
            *(s8*)&sAl[swz(row, sl)] = av;
            *(s8*)&sBl[swz(row, sl)] = *(const s8*)&Bb[(long)row * K + k0 + sl * 8];
        }
        __syncthreads();
#pragma unroll
        for (int ks = 0; ks < 2; ++ks) {
            s8 af[4], bg[4];
#pragma unroll
            for (int f = 0; f < 4; ++f) {
                af[f] = *(const s8*)&sAl[swz(wm + f * 16 + fr16, kq + 4 * ks)];
                bg[f] = *(const s8*)&sBl[swz(wn + f * 16 + fr16, kq + 4 * ks)];
            }
#pragma unroll
            for (int fr = 0; fr < 4; ++fr)
#pragma unroll
                for (int fc = 0; fc < 4; ++fc)
                    acc[fr][fc] = __builtin_amdgcn_mfma_f32_16x16x32_bf16(
                        af[fr], bg[fc], acc[fr][fc], 0, 0, 0);
        }
        __syncthreads();
    }
    float ps[4], ps2[4];
    if (PART) {
#pragma unroll
        for (int fc = 0; fc < 4; ++fc) { ps[fc] = 0.f; ps2[fc] = 0.f; }
    }
#pragma unroll
    for (int fr = 0; fr < 4; ++fr) {
        int rl = wm + fr * 16 + (lane >> 4) * 4;
#pragma unroll
        for (int fc = 0; fc < 4; ++fc) {
            int cl = wn + fc * 16 + (lane & 15);
            int col = n0 + cl;
            float bv = bias[col];
#pragma unroll
            for (int i = 0; i < 4; ++i) {
                float v = acc[fr][fc][i] + bv;
                if (EPI == 2) v = fmaxf(v, 0.f);
                if (PART) { ps[fc] += v; ps2[fc] += v * v; }
                if (OUT == 0) Cf[(long)(m0 + rl + i) * ldc + col] = v;
                if (OUT == 1) Cb[(long)(m0 + rl + i) * ldc + col] = f2bf(v);
            }
        }
    }
    if (PART) {
        __syncthreads();
        float* scr = (float*)sAl;
#pragma unroll
        for (int fc = 0; fc < 4; ++fc) {
            ps[fc] += __shfl_xor(ps[fc], 16);  ps[fc] += __shfl_xor(ps[fc], 32);
            ps2[fc] += __shfl_xor(ps2[fc], 16); ps2[fc] += __shfl_xor(ps2[fc], 32);
        }
        if (lane < 16) {
#pragma unroll
            for (int fc = 0; fc < 4; ++fc) {
                scr[(w * 2 + 0) * 64 + fc * 16 + lane] = ps[fc];
                scr[(w * 2 + 1) * 64 + fc * 16 + lane] = ps2[fc];
            }
        }
        __syncthreads();
        int id = blockIdx.x * gridDim.y + blockIdx.y;   // gridDim = (2, 256)
        int stat = t >> 7, c = t & 127;
        int ci = c & 63, half = c >> 6;
        float v = scr[(half * 2 + stat) * 64 + ci] + scr[((half + 2) * 2 + stat) * 64 + ci];
        part[(long)id * 256 + stat * 128 + c] = v;
    }
}

// ---------------- batchnorm finalize -> (scale, shift) ----------------
__global__ void k_bnfin(const float* __restrict__ part, const float* __restrict__ gam,
                        const float* __restrict__ bet, float* __restrict__ stats) {
    int ch = blockIdx.x;
    int half = ch >> 7, cc = ch & 127;
    int t = threadIdx.x;
    __shared__ float2 sm[256];
    const float* p = part + (long)(half * 256 + t) * 256;
    sm[t] = make_float2(p[cc], p[128 + cc]);
    __syncthreads();
    for (int s = 128; s > 0; s >>= 1) {
        if (t < s) { sm[t].x += sm[t + s].x; sm[t].y += sm[t + s].y; }
        __syncthreads();
    }
    if (t == 0) {
        float m = sm[0].x / (float)NN;
        float var = sm[0].y / (float)NN - m * m;
        float sc = rsqrtf(var + 1e-5f) * gam[ch];
        stats[ch]       = sc;
        stats[256 + ch] = bet[ch] - m * sc;
    }
}

// ---------------- final: BN-apply + residual + relu + L2-norm + col-max ----------------
__global__ __launch_bounds__(512) void k_finz(
    const bf* __restrict__ X, const float* __restrict__ stats,
    const bf* __restrict__ res, float* __restrict__ outz, bf* __restrict__ Znb,
    unsigned* __restrict__ zgu) {
    int g = blockIdx.x, half = blockIdx.y;
    int t = threadIdx.x;
    int lane = t & 63, w = t >> 6;
    int c4 = lane * 4;
    float4 sc = *(const float4*)&stats[c4];
    float4 sh = *(const float4*)&stats[256 + c4];
    float scv[4] = {sc.x, sc.y, sc.z, sc.w};
    float shv[4] = {sh.x, sh.y, sh.z, sh.w};
    float cmax[4] = {0.f, 0.f, 0.f, 0.f};
#pragma unroll
    for (int it = 0; it < 8; ++it) {
        int r = half * 64 + w * 8 + it;
        long i = (long)(g * 128 + r) * 256 + c4;
        ushort4 xv = *(const ushort4*)(X + i);
        ushort4 rv = *(const ushort4*)(res + i);
        unsigned short xs[4] = {xv.x, xv.y, xv.z, xv.w};
        unsigned short rs[4] = {rv.x, rv.y, rv.z, rv.w};
        float v[4];
        float s = 0.f;
#pragma unroll
        for (int j = 0; j < 4; ++j) {
            float vv = fmaf(u2f(xs[j]), scv[j], shv[j]);
            vv = fmaxf(vv, 0.f) + u2f(rs[j]);
            vv = fmaxf(vv, 0.f);
            v[j] = vv;
            s += vv * vv;
        }
#pragma unroll
        for (int o = 1; o < 64; o <<= 1) s += __shfl_xor(s, o);
        float den = fmaxf(sqrtf(s), 1e-12f);
        float4 fo;
        unsigned short us[4];
#pragma unroll
        for (int j = 0; j < 4; ++j) {
            float o = v[j] / den;
            ((float*)&fo)[j] = o;
            us[j] = f2u(o);
            cmax[j] = fmaxf(cmax[j], o);
        }
        *(float4*)(outz + i) = fo;
        *(ushort4*)(Znb + i) = make_ushort4(us[0], us[1], us[2], us[3]);
    }
    __shared__ float pm[8][256];
#pragma unroll
    for (int j = 0; j < 4; ++j) pm[w][c4 + j] = cmax[j];
    __syncthreads();
    if (t < 256) {
        float m = fmaxf(pm[0][t], pm[1][t]);
#pragma unroll
        for (int ww = 2; ww < 8; ++ww) m = fmaxf(m, pm[ww][t]);
        atomicMax(&zgu[g * 256 + t], __float_as_uint(m));
    }
}

// ---------------- host ----------------
template <int EPI, int OUT, bool PART, bool BNA, bool AF32>
static void MG(hipStream_t st, const void* A, const bf* BT, const float* bias,
               const float* bnstats, float* Cf, bf* Cb, float* part,
               int M, int N, int K, int ldc) {
    dim3 g(N / 128, M / 128, 1);
    mg<EPI, OUT, PART, BNA, AF32><<<g, 256, 0, st>>>(A, BT, bias, bnstats, Cf, Cb, part,
                                                     M, N, K, ldc);
}

extern "C" void kernel_launch(void* const* d_in, const int* in_sizes, int n_in,
                              void* d_out, int out_size, void* d_ws, size_t ws_size,
                              hipStream_t stream) {
    const float* x      = (const float*)d_in[0];
    const int*   srcL   = (const int*)d_in[1];
    const int*   dstL   = (const int*)d_in[2];
    const float* gcn_w0 = (const float*)d_in[3];
    const float* bn_g0  = (const float*)d_in[5];
    const float* bn_b0  = (const float*)d_in[6];
    const float* gcn_w1 = (const float*)d_in[7];
    const float* bn_g1  = (const float*)d_in[9];
    const float* bn_b1  = (const float*)d_in[10];
    const float* gcn_w2 = (const float*)d_in[11];
    const float* bn_g2  = (const float*)d_in[13];
    const float* bn_b2  = (const float*)d_in[14];
    const float* sc_w0  = (const float*)d_in[15];
    const float* sc_b0  = (const float*)d_in[16];
    const float* edge_w = (const float*)d_in[17];
    const float* fd_w0  = (const float*)d_in[18];
    const float* fd_b0  = (const float*)d_in[19];
    const float* fd_g0  = (const float*)d_in[20];
    const float* fd_be0 = (const float*)d_in[21];
    const float* fd_w1  = (const float*)d_in[22];
    const float* fd_b1  = (const float*)d_in[23];
    const float* fd_g1  = (const float*)d_in[24];
    const float* fd_be1 = (const float*)d_in[25];
    const float* fd_w2  = (const float*)d_in[26];
    const float* fd_b2  = (const float*)d_in[27];
    const float* ph_w0  = (const float*)d_in[28];
    const float* ph_b0  = (const float*)d_in[29];
    const float* ph_w1  = (const float*)d_in[30];
    const float* ph_b1  = (const float*)d_in[31];

    float* out     = (float*)d_out;
    float* out_z   = out;
    float* out_adj = out + 8388608;
    float* out_xr  = out + 12582912;
    float* out_zg  = out + 16777216;
    float* out_zgm = out + 16842752;

    float* w     = (float*)d_ws;
    float* part  = w;                        // 131072
    float* stats = w + 131072;               // 512
    bf*    wT    = (bf*)(w + 131584);        // 557056 bf16
    bf*    Aadjb = (bf*)(w + 410112);        // 4194304 bf16
    bf*    U4    = (bf*)(w + 2507264);       // 8388608 bf16
    bf*    U1    = (bf*)(w + 6701568);
    bf*    U2    = (bf*)(w + 10895872);
    bf*    U3    = (bf*)(w + 15090176);
    bf*    P1b   = (bf*)(w + 19284480);      // 65536 bf16
    bf*    xb    = (bf*)(w + 19317248);      // 4194304 bf16

    WTpack pk;
    pk.w[0] = {gcn_w0, 128, 256, 0};
    pk.w[1] = {sc_w0,  128, 256, 32768};
    pk.w[2] = {gcn_w1, 256, 256, 65536};
    pk.w[3] = {gcn_w2, 256, 256, 131072};
    pk.w[4] = {edge_w, 256, 256, 196608};
    pk.w[5] = {fd_w0,  256, 256, 262144};
    pk.w[6] = {fd_w1,  256, 256, 327680};
    pk.w[7] = {fd_w2,  256, 128, 393216};
    pk.w[8] = {ph_w0,  256, 256, 425984};
    pk.w[9] = {ph_w1,  256, 256, 491520};

    // zero out_zg early (atomicMax target; harness poisons d_out)
    hipMemsetAsync(out_zg, 0, 65536 * 4, stream);

    // --- prep: adjacency + weight transpose + x->bf16 ---
    k_prep<<<672, 256, 0, stream>>>(srcL, dstL, x, pk, Aadjb, xb, wT);

    // --- layer 0 (grid 256x4): AG0 -> U2, res0 -> U1 ---
    k_fused<2><<<dim3(256, 4), 512, 0, stream>>>(xb, nullptr, nullptr,
                                                 wT + 0, wT + 32768, sc_b0, Aadjb,
                                                 nullptr, U2, U1, part);
    k_bnfin<<<256, 256, 0, stream>>>(part, bn_g0, bn_b0, stats);

    // --- layer 1 (grid 256x2): Z0 -> U3, AG1 -> U4 ---
    k_fused<0><<<dim3(256, 2), 512, 0, stream>>>(U2, U1, stats,
                                                 wT + 65536, nullptr, nullptr, Aadjb,
                                                 U3, U4, nullptr, part);
    k_bnfin<<<256, 256, 0, stream>>>(part, bn_g1, bn_b1, stats);

    // --- layer 2: Z1 -> U1, AG2 -> U2 ---
    k_fused<0><<<dim3(256, 2), 512, 0, stream>>>(U4, U3, stats,
                                                 wT + 131072, nullptr, nullptr, Aadjb,
                                                 U1, U2, nullptr, part);
    k_bnfin<<<256, 256, 0, stream>>>(part, bn_g2, bn_b2, stats);

    // --- BN-apply + L2 + col-max: AG2 (U2), res Z1 (U1) -> out_z, Zn (U3), zg ---
    k_finz<<<dim3(256, 2), 512, 0, stream>>>(U2, stats, U1, out_z, U3,
                                             (unsigned*)out_zg);

    // --- edge decoder + fd0 + ph0, one dispatch ---
    k_edfd<<<772, 512, 0, stream>>>(U3, wT + 196608, wT + 262144, fd_b0,
                                    out_zg, wT + 425984, ph_b0,
                                    out_adj, U4, part, P1b);
    k_bnfin<<<256, 256, 0, stream>>>(part, fd_g0, fd_be0, stats);

    // --- feature decoder (fd1, fd2) ---
    MG<2, 1, true, true, false>(stream, U4, wT + 327680, fd_b1, stats,
                                nullptr, U2, part, NN, HD, HD, 256);
    k_bnfin<<<256, 256, 0, stream>>>(part, fd_g1, fd_be1, stats);
    MG<1, 0, false, true, false>(stream, U2, wT + 393216, fd_b2, stats,
                                 out_xr, nullptr, nullptr, NN, 128, HD, 128);

    // --- pooling head tail (ph1 reads P1b from edfd's ph0) ---
    MG<1, 0, false, false, false>(stream, P1b, wT + 491520, ph_b1, nullptr,
                                  out_zgm, nullptr, nullptr, 256, 256, 256, 256);
}

// Round 17
// 175.488 us; speedup vs baseline: 3.3370x; 1.0138x over previous
//
#include <hip/hip_runtime.h>
#include <hip/hip_bf16.h>

using bf = __hip_bfloat16;
typedef __attribute__((ext_vector_type(8))) short s8;
typedef __attribute__((ext_vector_type(4))) float f4;

constexpr int NN  = 32768;
constexpr int HD  = 256;

__device__ __forceinline__ float u2f(unsigned short h) {
    union { unsigned u; float f; } x; x.u = ((unsigned)h) << 16;
    return x.f;
}
__device__ __forceinline__ unsigned short f2u(float f) {
    union { float f; unsigned u; } x; x.f = f;
    unsigned r = x.u + 0x7FFF + ((x.u >> 16) & 1);
    return (unsigned short)(r >> 16);
}
__device__ __forceinline__ bf f2bf(float f) {
    unsigned short h = f2u(f);
    return *reinterpret_cast<bf*>(&h);
}
__device__ __forceinline__ float bf2f(bf b) {
    return u2f(*reinterpret_cast<unsigned short*>(&b));
}

__device__ __forceinline__ int swz(int row, int slot) {      // 64-col rows
    return row * 64 + ((slot ^ (row & 7)) << 3);
}
__device__ __forceinline__ int swz128(int row, int slot) {   // 128-col rows
    return row * 128 + ((slot ^ (row & 7)) << 3);
}

// async global->LDS, 16B per lane; LDS dest = wave-uniform base + lane*16.
typedef const __attribute__((address_space(1))) unsigned int guint;
typedef __attribute__((address_space(3))) unsigned int luint;
__device__ __forceinline__ void gload16(const void* g, void* l) {
    __builtin_amdgcn_global_load_lds((guint*)g, (luint*)l, 16, 0, 0);
}

// ---------------- prep: adjacency + weight transpose + x cvt, one dispatch ----
struct WTd { const float* src; int K, N, off; };
struct WTpack { WTd w[10]; };

__global__ __launch_bounds__(256) void k_prep(const int* __restrict__ srcL,
                                              const int* __restrict__ dstL,
                                              const float* __restrict__ xf,
                                              WTpack p, bf* __restrict__ A,
                                              bf* __restrict__ xb,
                                              bf* __restrict__ wT) {
    __shared__ __align__(16) float shm[8320];
    int b = blockIdx.x, t = threadIdx.x;
    if (b < 256) {
        float* sT = shm;
        float* sdin = shm + 8192;
        int g = b;
        const int* sg = srcL + (g << 11);
        const int* dg = dstL + (g << 11);
        if (t < 128) sdin[t] = 0.f;
        __syncthreads();
        for (int e = t; e < 2048; e += 256) atomicAdd(&sdin[dg[e]], 1.0f);
        __syncthreads();
        if (t < 128) sdin[t] = rsqrtf(sdin[t] + 1.0f);
        __syncthreads();
        bf* out = A + ((long)g << 14);
        for (int half = 0; half < 2; ++half) {
            for (int i = t; i < 8192; i += 256) sT[i] = 0.f;
            __syncthreads();
            for (int e = t; e < 2048; e += 256) {
                int s = sg[e], d = dg[e];
                if ((s >> 6) == half)
                    atomicAdd(&sT[(d << 6) + (s & 63)], sdin[s] * sdin[d]);
            }
            __syncthreads();
            if (t < 128 && (t >> 6) == half)
                sT[(t << 6) + (t & 63)] += sdin[t] * sdin[t];
            __syncthreads();
            for (int i4 = t; i4 < 2048; i4 += 256) {
                int d = i4 >> 4, c4 = (i4 & 15) * 4;
                float4 v = *(float4*)&sT[(d << 6) + c4];
                ushort4 u = make_ushort4(f2u(v.x), f2u(v.y), f2u(v.z), f2u(v.w));
                *(ushort4*)&out[(d << 7) + (half << 6) + c4] = u;
            }
            __syncthreads();
        }
    } else if (b < 416) {
        int idx = b - 256;
        WTd d = p.w[idx >> 4];
        int rem = idx & 15;
        int n0 = (rem & 3) * 64, k0 = (rem >> 2) * 64;
        if (n0 >= d.N || k0 >= d.K) return;
        float (*s)[65] = (float(*)[65])shm;
        int cc = t & 63, rq = t >> 6;
#pragma unroll
        for (int i = 0; i < 16; ++i) {
            int r = i * 4 + rq;
            s[r][cc] = d.src[(long)(k0 + r) * d.N + n0 + cc];
        }
        __syncthreads();
#pragma unroll
        for (int i = 0; i < 16; ++i) {
            int r = i * 4 + rq;
            wT[d.off + (long)(n0 + r) * d.K + k0 + cc] = f2bf(s[cc][r]);
        }
    } else {
        long base = (long)(b - 416) * 16384;
#pragma unroll
        for (int it = 0; it < 16; ++it) {
            long i4 = base + (it * 256 + t) * 4;
            float4 v = *(const float4*)&xf[i4];
            *(ushort4*)&xb[i4] = make_ushort4(f2u(v.x), f2u(v.y), f2u(v.z), f2u(v.w));
        }
    }
}

// ---------------- MFMA helpers (512-thr per-graph kernels) ----------------
__device__ __forceinline__ void mfma_s1(const bf* sA, const bf* sB, f4 (&acc)[4][2],
                                        int wm, int wn, int l15, int kq) {
#pragma unroll
    for (int ks = 0; ks < 2; ++ks) {
        s8 af[4], bg[2];
#pragma unroll
        for (int f = 0; f < 4; ++f)
            af[f] = *(const s8*)&sA[swz(wm * 64 + f * 16 + l15, kq + 4 * ks)];
#pragma unroll
        for (int f = 0; f < 2; ++f)
            bg[f] = *(const s8*)&sB[swz(wn * 32 + f * 16 + l15, kq + 4 * ks)];
#pragma unroll
        for (int fr = 0; fr < 4; ++fr)
#pragma unroll
            for (int fc = 0; fc < 2; ++fc)
                acc[fr][fc] = __builtin_amdgcn_mfma_f32_16x16x32_bf16(
                    af[fr], bg[fc], acc[fr][fc], 0, 0, 0);
    }
}

__device__ __forceinline__ void mfma_s2(const bf* sA, const bf* sB, f4 (&acc)[4][2],
                                        int wm, int wn, int l15, int kq) {
#pragma unroll
    for (int ks = 0; ks < 4; ++ks) {
        s8 af[4], bg[2];
#pragma unroll
        for (int f = 0; f < 4; ++f)
            af[f] = *(const s8*)&sA[swz128(wm * 64 + f * 16 + l15, ks * 4 + kq)];
#pragma unroll
        for (int f = 0; f < 2; ++f)
            bg[f] = *(const s8*)&sB[swz128(wn * 32 + f * 16 + l15, ks * 4 + kq)];
#pragma unroll
        for (int fr = 0; fr < 4; ++fr)
#pragma unroll
            for (int fc = 0; fc < 2; ++fc)
                acc[fr][fc] = __builtin_amdgcn_mfma_f32_16x16x32_bf16(
                    af[fr], bg[fc], acc[fr][fc], 0, 0, 0);
    }
}

__device__ __forceinline__ void tstore(bf* sOut, f4 (&acc)[4][2],
                                       int wm, int wn, int l15, int kq) {
#pragma unroll
    for (int fr = 0; fr < 4; ++fr) {
        int rl = wm * 64 + fr * 16 + kq * 4;
#pragma unroll
        for (int fc = 0; fc < 2; ++fc) {
            int cl = wn * 32 + fc * 16 + l15;
            ushort4 q = make_ushort4(f2u(acc[fr][fc][0]), f2u(acc[fr][fc][1]),
                                     f2u(acc[fr][fc][2]), f2u(acc[fr][fc][3]));
            int off = cl * 128 + (((rl >> 3) ^ (cl & 7)) << 3) + (rl & 7);
            *(ushort4*)&sOut[off] = q;
        }
    }
}

// ---------------- stage-1 staging step (one 64-col K-slab into dst) ----------------
template <int MODE>
__device__ __forceinline__ void stg1(const bf* Xg, const bf* Rg,
                                     const float* stats, const bf* Wt,
                                     const bf* Wt2, bf* Zout, bf* dst,
                                     int g, int h, int k0, int t, int lane, int w) {
#pragma unroll
    for (int i = 0; i < 2; ++i) {
        if constexpr (MODE == 0) {
            int sdx = i * 512 + t;
            int row = sdx >> 3, sl = sdx & 7;
            int c = k0 + sl * 8;
            s8 av = *(const s8*)&Xg[row * 256 + c];
            s8 rv = *(const s8*)&Rg[row * 256 + c];
            float4 sc0 = *(const float4*)&stats[c];
            float4 sc1 = *(const float4*)&stats[c + 4];
            float4 sh0 = *(const float4*)&stats[256 + c];
            float4 sh1 = *(const float4*)&stats[256 + c + 4];
            float scv[8] = {sc0.x, sc0.y, sc0.z, sc0.w, sc1.x, sc1.y, sc1.z, sc1.w};
            float shv[8] = {sh0.x, sh0.y, sh0.z, sh0.w, sh1.x, sh1.y, sh1.z, sh1.w};
            unsigned short* u = (unsigned short*)&av;
            const unsigned short* ru = (const unsigned short*)&rv;
#pragma unroll
            for (int j = 0; j < 8; ++j) {
                float v = fmaf(u2f(u[j]), scv[j], shv[j]);
                v = fmaxf(v, 0.f) + u2f(ru[j]);
                u[j] = f2u(fmaxf(v, 0.f));
            }
            if (h == 0)
                *(s8*)&Zout[(long)g * 32768 + row * 256 + c] = av;
            *(s8*)&dst[swz(row, sl)] = av;
        } else {
            int r0 = i * 64 + 8 * w;
            int rw = r0 + (lane >> 3);
            int ps = ((lane & 7) ^ (rw & 7)) << 3;
            gload16(&Xg[rw * 128 + k0 + ps], &dst[r0 * 64]);
        }
        {
            int r0 = i * 64 + 8 * w;
            int rw = r0 + (lane >> 3);
            int ps = ((lane & 7) ^ (rw & 7)) << 3;
            const bf* bsrc;
            if constexpr (MODE == 0)
                bsrc = &Wt[(h * 128 + rw) * 256 + k0 + ps];
            else {
                const bf* Wsrc = (h < 2) ? Wt : Wt2;
                bsrc = &Wsrc[((h & 1) * 128 + rw) * 128 + k0 + ps];
            }
            gload16(bsrc, &dst[8192 + r0 * 64]);
        }
    }
}

// ---------------- fused per-graph kernels (double-buffered stage 1) ----------------
// MODE 0 (grid 256x2): GCN layer, phase hb = blockIdx.y (independent col-halves)
// MODE 2 (grid 256x4): layer 0; phases 0,1 = GCN halves; 2,3 = shortcut halves
template <int MODE>
__global__ __launch_bounds__(512) void k_fused(
    const bf* __restrict__ Xin,
    const bf* __restrict__ Res, const float* __restrict__ stats,
    const bf* __restrict__ Wt, const bf* __restrict__ Wt2,
    const float* __restrict__ scb, const bf* __restrict__ Adj,
    bf* __restrict__ Zout, bf* __restrict__ AG, bf* __restrict__ ResOut,
    float* __restrict__ part) {
    __shared__ __align__(16) bf sOut[16384];
    __shared__ __align__(16) bf sStg[16384];
    const int g = blockIdx.x;
    const int h = blockIdx.y;
    const int t = threadIdx.x;
    const int lane = t & 63, w = t >> 6;
    const int wm = w >> 2, wn = w & 3;
    const int l15 = lane & 15, kq = lane >> 4;
    constexpr int KS1 = (MODE == 2) ? 128 : 256;
    constexpr int NK = KS1 / 64;
    const bf* Xg = Xin + (long)g * ((MODE == 2) ? 16384 : 32768);
    const bf* Rg = (MODE == 0) ? Res + (long)g * 32768 : nullptr;

    // ---- stage 1: double-buffered (sStg even, sOut odd); one barrier per K-step ----
    f4 acc1[4][2] = {};
    stg1<MODE>(Xg, Rg, stats, Wt, Wt2, Zout, sStg, g, h, 0, t, lane, w);
    __syncthreads();
#pragma unroll
    for (int k = 0; k < NK; ++k) {
        bf* cur = (k & 1) ? sOut : sStg;
        if (k + 1 < NK)
            stg1<MODE>(Xg, Rg, stats, Wt, Wt2, Zout, (k & 1) ? sStg : sOut,
                       g, h, (k + 1) * 64, t, lane, w);
        mfma_s1(cur, cur + 8192, acc1, wm, wn, l15, kq);
        __syncthreads();
    }
    if (MODE == 2 && h >= 2) {
        // shortcut: direct row-major write + bias
#pragma unroll
        for (int fr = 0; fr < 4; ++fr) {
            int rl = wm * 64 + fr * 16 + kq * 4;
#pragma unroll
            for (int fc = 0; fc < 2; ++fc) {
                int cl = wn * 32 + fc * 16 + l15;
                float bv = scb[(h - 2) * 128 + cl];
#pragma unroll
                for (int i = 0; i < 4; ++i)
                    ResOut[(long)(g * 128 + rl + i) * 256 + (h - 2) * 128 + cl] =
                        f2bf(acc1[fr][fc][i] + bv);
            }
        }
        return;
    }
    // ---- HT transposed into sStg (last stage-1 reads were from sOut); Adj into sOut ----
    tstore(sStg, acc1, wm, wn, l15, kq);
#pragma unroll
    for (int i = 0; i < 4; ++i) {
        int r0 = i * 32 + 4 * w;
        int rw = r0 + (lane >> 4);
        int ps = ((lane & 15) ^ (rw & 7)) << 3;
        gload16(&Adj[((long)g << 14) + rw * 128 + ps], &sOut[r0 * 128]);
    }
    __syncthreads();
    f4 acc2[4][2] = {};
    mfma_s2(sOut, sStg, acc2, wm, wn, l15, kq);
    // ---- AG write + BN partials ----
    float ps[2] = {0.f, 0.f}, ps2[2] = {0.f, 0.f};
#pragma unroll
    for (int fr = 0; fr < 4; ++fr) {
        int rl = wm * 64 + fr * 16 + kq * 4;
#pragma unroll
        for (int fc = 0; fc < 2; ++fc) {
            int cl = wn * 32 + fc * 16 + l15;
#pragma unroll
            for (int i = 0; i < 4; ++i) {
                float v = acc2[fr][fc][i];
                ps[fc] += v; ps2[fc] += v * v;
                AG[(long)(g * 128 + rl + i) * 256 + (h & 1) * 128 + cl] = f2bf(v);
            }
        }
    }
    __syncthreads();
    float* scr = (float*)sStg;
#pragma unroll
    for (int fc = 0; fc < 2; ++fc) {
        ps[fc] += __shfl_xor(ps[fc], 16);  ps[fc] += __shfl_xor(ps[fc], 32);
        ps2[fc] += __shfl_xor(ps2[fc], 16); ps2[fc] += __shfl_xor(ps2[fc], 32);
    }
    if (lane < 16) {
#pragma unroll
        for (int fc = 0; fc < 2; ++fc) {
            int c = wn * 32 + fc * 16 + lane;
            scr[(c * 2 + wm) * 2 + 0] = ps[fc];
            scr[(c * 2 + wm) * 2 + 1] = ps2[fc];
        }
    }
    __syncthreads();
    if (t < 256) {
        int col = t & 127, s = t >> 7;
        part[(long)((h & 1) * 256 + g) * 256 + s * 128 + col] =
            scr[(col * 2 + 0) * 2 + s] + scr[(col * 2 + 1) * 2 + s];
    }
}

// ---------------- fd stage-1 layer (device fn, used by k_edfd) ----------------
__device__ __forceinline__ void fd_layer(const bf* Zg, const bf* W, const float* bias,
                                         bf* C, float* part, bf* sStg,
                                         int g, int h, int t, int lane,
                                         int wm, int wn, int l15, int kq) {
    f4 acc[4][2] = {};
    for (int k0 = 0; k0 < 256; k0 += 64) {
        __syncthreads();
#pragma unroll
        for (int i = 0; i < 2; ++i) {
            int sdx = i * 512 + t;
            int row = sdx >> 3, sl = sdx & 7;
            int c = k0 + sl * 8;
            *(s8*)&sStg[swz(row, sl)] = *(const s8*)&Zg[row * 256 + c];
            *(s8*)&sStg[8192 + swz(row, sl)] = *(const s8*)&W[(h * 128 + row) * 256 + c];
        }
        __syncthreads();
        mfma_s1(sStg, sStg + 8192, acc, wm, wn, l15, kq);
    }
    float ps[2] = {0.f, 0.f}, ps2[2] = {0.f, 0.f};
#pragma unroll
    for (int fr = 0; fr < 4; ++fr) {
        int rl = wm * 64 + fr * 16 + kq * 4;
#pragma unroll
        for (int fc = 0; fc < 2; ++fc) {
            int cl = wn * 32 + fc * 16 + l15;
            float bv = bias[h * 128 + cl];
#pragma unroll
            for (int i = 0; i < 4; ++i) {
                float v = fmaxf(acc[fr][fc][i] + bv, 0.f);
                ps[fc] += v; ps2[fc] += v * v;
                C[(long)(g * 128 + rl + i) * 256 + h * 128 + cl] = f2bf(v);
            }
        }
    }
    __syncthreads();
    float* scr = (float*)sStg;
#pragma unroll
    for (int fc = 0; fc < 2; ++fc) {
        ps[fc] += __shfl_xor(ps[fc], 16);  ps[fc] += __shfl_xor(ps[fc], 32);
        ps2[fc] += __shfl_xor(ps2[fc], 16); ps2[fc] += __shfl_xor(ps2[fc], 32);
    }
    if (lane < 16) {
#pragma unroll
        for (int fc = 0; fc < 2; ++fc) {
            int c = wn * 32 + fc * 16 + lane;
            scr[(c * 2 + wm) * 2 + 0] = ps[fc];
            scr[(c * 2 + wm) * 2 + 1] = ps2[fc];
        }
    }
    __syncthreads();
    if (t < 256) {
        int col = t & 127, s = t >> 7;
        part[(long)(h * 256 + g) * 256 + s * 128 + col] =
            scr[(col * 2 + 0) * 2 + s] + scr[(col * 2 + 1) * 2 + s];
    }
}

// ---------------- edge decoder + fd0 + ph0, one dispatch (772 blocks) ----------------
__global__ __launch_bounds__(512) void k_edfd(
    const bf* __restrict__ Zn, const bf* __restrict__ ewT,
    const bf* __restrict__ fdw, const float* __restrict__ fdb,
    const float* __restrict__ zgf, const bf* __restrict__ phw,
    const float* __restrict__ phb,
    float* __restrict__ adjout, bf* __restrict__ C, float* __restrict__ part,
    bf* __restrict__ P1b) {
    __shared__ __align__(16) bf sOut[16384];
    __shared__ __align__(16) bf sStg[16384];
    const int t = threadIdx.x;
    const int lane = t & 63, w = t >> 6;
    const int wm = w >> 2, wn = w & 3;
    const int l15 = lane & 15, kq = lane >> 4;
    if (blockIdx.x >= 768) {
        // ---- ph0: P1 = relu(zg @ phw^T + phb), zg f32 [256][256] ----
        int bb = blockIdx.x - 768;
        int gz = bb & 1, h = bb >> 1;
        f4 acc[4][2] = {};
        for (int k0 = 0; k0 < 256; k0 += 64) {
            __syncthreads();
#pragma unroll
            for (int i = 0; i < 2; ++i) {
                int sdx = i * 512 + t;
                int row = sdx >> 3, sl = sdx & 7;
                int c = k0 + sl * 8;
                const float* src = zgf + (long)(gz * 128 + row) * 256 + c;
                float4 f0 = *(const float4*)src;
                float4 f1 = *(const float4*)(src + 4);
                unsigned short u[8] = {f2u(f0.x), f2u(f0.y), f2u(f0.z), f2u(f0.w),
                                       f2u(f1.x), f2u(f1.y), f2u(f1.z), f2u(f1.w)};
                *(s8*)&sStg[swz(row, sl)] = *(s8*)u;
                *(s8*)&sStg[8192 + swz(row, sl)] =
                    *(const s8*)&phw[(h * 128 + row) * 256 + c];
            }
            __syncthreads();
            mfma_s1(sStg, sStg + 8192, acc, wm, wn, l15, kq);
        }
#pragma unroll
        for (int fr = 0; fr < 4; ++fr) {
            int rl = wm * 64 + fr * 16 + kq * 4;
#pragma unroll
            for (int fc = 0; fc < 2; ++fc) {
                int cl = wn * 32 + fc * 16 + l15;
                float bv = phb[h * 128 + cl];
#pragma unroll
                for (int i = 0; i < 4; ++i)
                    P1b[(long)(gz * 128 + rl + i) * 256 + h * 128 + cl] =
                        f2bf(fmaxf(acc[fr][fc][i] + bv, 0.f));
            }
        }
        return;
    }
    if (blockIdx.x >= 256) {
        int bb = blockIdx.x - 256;
        int g = bb & 255, h = bb >> 8;
        fd_layer(Zn + (long)g * 32768, fdw, fdb, C, part, sStg,
                 g, h, t, lane, wm, wn, l15, kq);
        return;
    }
    const int g = blockIdx.x;
    const bf* Xg = Zn + (long)g * 32768;
    f4 acc2[4][2] = {};
    for (int h = 0; h < 2; ++h) {
        f4 acc1[4][2] = {};
        for (int k0 = 0; k0 < 256; k0 += 64) {
            __syncthreads();
#pragma unroll
            for (int i = 0; i < 2; ++i) {
                int sdx = i * 512 + t;
                int row = sdx >> 3, sl = sdx & 7;
                int c = k0 + sl * 8;
                *(s8*)&sStg[swz(row, sl)] = *(const s8*)&ewT[(h * 128 + row) * 256 + c];
                *(s8*)&sStg[8192 + swz(row, sl)] = *(const s8*)&Xg[row * 256 + c];
            }
            __syncthreads();
            mfma_s1(sStg, sStg + 8192, acc1, wm, wn, l15, kq);
        }
        tstore(sOut, acc1, wm, wn, l15, kq);
        __syncthreads();
#pragma unroll
        for (int i = 0; i < 4; ++i) {
            int sdx = i * 512 + t;
            int row = sdx >> 4, sl = sdx & 15;
            *(s8*)&sStg[swz128(row, sl)] = *(const s8*)&Xg[row * 256 + h * 128 + sl * 8];
        }
        __syncthreads();
        mfma_s2(sStg, sOut, acc2, wm, wn, l15, kq);
        __syncthreads();
    }
#pragma unroll
    for (int fr = 0; fr < 4; ++fr) {
        int rl = wm * 64 + fr * 16 + kq * 4;
#pragma unroll
        for (int fc = 0; fc < 2; ++fc) {
            int cl = wn * 32 + fc * 16 + l15;
            float vv[4];
#pragma unroll
            for (int i = 0; i < 4; ++i) {
                float v = 1.f / (1.f + __expf(-acc2[fr][fc][i]));
                if (cl == rl + i) v = 0.f;
                vv[i] = v;
            }
            float4 o; o.x = vv[0]; o.y = vv[1]; o.z = vv[2]; o.w = vv[3];
            *(float4*)&adjout[((long)g << 14) + cl * 128 + rl] = o;
        }
    }
}

// ---------------- MFMA GEMM (fd1/fd2/ph1) ----------------
template <int EPI, int OUT, bool PART, bool BNA, bool AF32>
__global__ __launch_bounds__(256) void mg(
    const void* __restrict__ Av, const bf* __restrict__ BT,
    const float* __restrict__ bias, const float* __restrict__ bnstats,
    float* __restrict__ Cf, bf* __restrict__ Cb, float* __restrict__ part,
    int M, int N, int K, int ldc) {
    __shared__ __align__(16) bf sAl[128 * 64];
    __shared__ __align__(16) bf sBl[128 * 64];
    const int m0 = blockIdx.y * 128, n0 = blockIdx.x * 128;
    const bf* Bb = BT + (long)n0 * K;
    const int t = threadIdx.x;
    const int lane = t & 63;
    const int w = t >> 6;
    const int wm = (w >> 1) * 64, wn = (w & 1) * 64;
    const int fr16 = lane & 15, kq = lane >> 4;
    f4 acc[4][4] = {};
    for (int k0 = 0; k0 < K; k0 += 64) {
#pragma unroll
        for (int i = 0; i < 4; ++i) {
            int sdx = i * 256 + t;
            int row = sdx >> 3, sl = sdx & 7;
            s8 av;
            if constexpr (AF32) {
                const float* src = (const float*)Av + (long)(m0 + row) * K + k0 + sl * 8;
                float4 f0 = *(const float4*)src;
                float4 f1 = *(const float4*)(src + 4);
                unsigned short u[8] = {f2u(f0.x), f2u(f0.y), f2u(f0.z), f2u(f0.w),
                                       f2u(f1.x), f2u(f1.y), f2u(f1.z), f2u(f1.w)};
                av = *(s8*)u;
            } else {
                av = *(const s8*)&((const bf*)Av)[(long)(m0 + row) * K + k0 + sl * 8];
                if constexpr (BNA) {
                    int c = k0 + sl * 8;
                    float4 sc0 = *(const float4*)&bnstats[c];
                    float4 sc1 = *(const float4*)&bnstats[c + 4];
                    float4 sh0 = *(const float4*)&bnstats[256 + c];
                    float4 sh1 = *(const float4*)&bnstats[256 + c + 4];
                    float scv[8] = {sc0.x, sc0.y, sc0.z, sc0.w, sc1.x, sc1.y, sc1.z, sc1.w};
                    float shv[8] = {sh0.x, sh0.y, sh0.z, sh0.w, sh1.x, sh1.y, sh1.z, sh1.w};
                    unsigned short* u = (unsigned short*)&av;
#pragma unroll
                    for (int j = 0; j < 8; ++j)
                        u[j] = f2u(fmaf(u2f(u[j]), scv[j], shv[j]));
                }
            }
            *(s8*)&sAl[swz(row, sl)] = av;
            *(s8*)&sBl[swz(row, sl)] = *(const s8*)&Bb[(long)row * K + k0 + sl * 8];
        }
        __syncthreads();
#pragma unroll
        for (int ks = 0; ks < 2; ++ks) {
            s8 af[4], bg[4];
#pragma unroll
            for (int f = 0; f < 4; ++f) {
                af[f] = *(const s8*)&sAl[swz(wm + f * 16 + fr16, kq + 4 * ks)];
                bg[f] = *(const s8*)&sBl[swz(wn + f * 16 + fr16, kq + 4 * ks)];
            }
#pragma unroll
            for (int fr = 0; fr < 4; ++fr)
#pragma unroll
                for (int fc = 0; fc < 4; ++fc)
                    acc[fr][fc] = __builtin_amdgcn_mfma_f32_16x16x32_bf16(
                        af[fr], bg[fc], acc[fr][fc], 0, 0, 0);
        }
        __syncthreads();
    }
    float ps[4], ps2[4];
    if (PART) {
#pragma unroll
        for (int fc = 0; fc < 4; ++fc) { ps[fc] = 0.f; ps2[fc] = 0.f; }
    }
#pragma unroll
    for (int fr = 0; fr < 4; ++fr) {
        int rl = wm + fr * 16 + (lane >> 4) * 4;
#pragma unroll
        for (int fc = 0; fc < 4; ++fc) {
            int cl = wn + fc * 16 + (lane & 15);
            int col = n0 + cl;
            float bv = bias[col];
#pragma unroll
            for (int i = 0; i < 4; ++i) {
                float v = acc[fr][fc][i] + bv;
                if (EPI == 2) v = fmaxf(v, 0.f);
                if (PART) { ps[fc] += v; ps2[fc] += v * v; }
                if (OUT == 0) Cf[(long)(m0 + rl + i) * ldc + col] = v;
                if (OUT == 1) Cb[(long)(m0 + rl + i) * ldc + col] = f2bf(v);
            }
        }
    }
    if (PART) {
        __syncthreads();
        float* scr = (float*)sAl;
#pragma unroll
        for (int fc = 0; fc < 4; ++fc) {
            ps[fc] += __shfl_xor(ps[fc], 16);  ps[fc] += __shfl_xor(ps[fc], 32);
            ps2[fc] += __shfl_xor(ps2[fc], 16); ps2[fc] += __shfl_xor(ps2[fc], 32);
        }
        if (lane < 16) {
#pragma unroll
            for (int fc = 0; fc < 4; ++fc) {
                scr[(w * 2 + 0) * 64 + fc * 16 + lane] = ps[fc];
                scr[(w * 2 + 1) * 64 + fc * 16 + lane] = ps2[fc];
            }
        }
        __syncthreads();
        int id = blockIdx.x * gridDim.y + blockIdx.y;   // gridDim = (2, 256)
        int stat = t >> 7, c = t & 127;
        int ci = c & 63, half = c >> 6;
        float v = scr[(half * 2 + stat) * 64 + ci] + scr[((half + 2) * 2 + stat) * 64 + ci];
        part[(long)id * 256 + stat * 128 + c] = v;
    }
}

// ---------------- batchnorm finalize -> (scale, shift) ----------------
__global__ void k_bnfin(const float* __restrict__ part, const float* __restrict__ gam,
                        const float* __restrict__ bet, float* __restrict__ stats) {
    int ch = blockIdx.x;
    int half = ch >> 7, cc = ch & 127;
    int t = threadIdx.x;
    __shared__ float2 sm[256];
    const float* p = part + (long)(half * 256 + t) * 256;
    sm[t] = make_float2(p[cc], p[128 + cc]);
    __syncthreads();
    for (int s = 128; s > 0; s >>= 1) {
        if (t < s) { sm[t].x += sm[t + s].x; sm[t].y += sm[t + s].y; }
        __syncthreads();
    }
    if (t == 0) {
        float m = sm[0].x / (float)NN;
        float var = sm[0].y / (float)NN - m * m;
        float sc = rsqrtf(var + 1e-5f) * gam[ch];
        stats[ch]       = sc;
        stats[256 + ch] = bet[ch] - m * sc;
    }
}

// ---------------- final: BN-apply + residual + relu + L2-norm + col-max ----------------
__global__ __launch_bounds__(512) void k_finz(
    const bf* __restrict__ X, const float* __restrict__ stats,
    const bf* __restrict__ res, float* __restrict__ outz, bf* __restrict__ Znb,
    unsigned* __restrict__ zgu) {
    int g = blockIdx.x, half = blockIdx.y;
    int t = threadIdx.x;
    int lane = t & 63, w = t >> 6;
    int c4 = lane * 4;
    float4 sc = *(const float4*)&stats[c4];
    float4 sh = *(const float4*)&stats[256 + c4];
    float scv[4] = {sc.x, sc.y, sc.z, sc.w};
    float shv[4] = {sh.x, sh.y, sh.z, sh.w};
    float cmax[4] = {0.f, 0.f, 0.f, 0.f};
#pragma unroll
    for (int it = 0; it < 8; ++it) {
        int r = half * 64 + w * 8 + it;
        long i = (long)(g * 128 + r) * 256 + c4;
        ushort4 xv = *(const ushort4*)(X + i);
        ushort4 rv = *(const ushort4*)(res + i);
        unsigned short xs[4] = {xv.x, xv.y, xv.z, xv.w};
        unsigned short rs[4] = {rv.x, rv.y, rv.z, rv.w};
        float v[4];
        float s = 0.f;
#pragma unroll
        for (int j = 0; j < 4; ++j) {
            float vv = fmaf(u2f(xs[j]), scv[j], shv[j]);
            vv = fmaxf(vv, 0.f) + u2f(rs[j]);
            vv = fmaxf(vv, 0.f);
            v[j] = vv;
            s += vv * vv;
        }
#pragma unroll
        for (int o = 1; o < 64; o <<= 1) s += __shfl_xor(s, o);
        float den = fmaxf(sqrtf(s), 1e-12f);
        float4 fo;
        unsigned short us[4];
#pragma unroll
        for (int j = 0; j < 4; ++j) {
            float o = v[j] / den;
            ((float*)&fo)[j] = o;
            us[j] = f2u(o);
            cmax[j] = fmaxf(cmax[j], o);
        }
        *(float4*)(outz + i) = fo;
        *(ushort4*)(Znb + i) = make_ushort4(us[0], us[1], us[2], us[3]);
    }
    __shared__ float pm[8][256];
#pragma unroll
    for (int j = 0; j < 4; ++j) pm[w][c4 + j] = cmax[j];
    __syncthreads();
    if (t < 256) {
        float m = fmaxf(pm[0][t], pm[1][t]);
#pragma unroll
        for (int ww = 2; ww < 8; ++ww) m = fmaxf(m, pm[ww][t]);
        atomicMax(&zgu[g * 256 + t], __float_as_uint(m));
    }
}

// ---------------- host ----------------
template <int EPI, int OUT, bool PART, bool BNA, bool AF32>
static void MG(hipStream_t st, const void* A, const bf* BT, const float* bias,
               const float* bnstats, float* Cf, bf* Cb, float* part,
               int M, int N, int K, int ldc) {
    dim3 g(N / 128, M / 128, 1);
    mg<EPI, OUT, PART, BNA, AF32><<<g, 256, 0, st>>>(A, BT, bias, bnstats, Cf, Cb, part,
                                                     M, N, K, ldc);
}

extern "C" void kernel_launch(void* const* d_in, const int* in_sizes, int n_in,
                              void* d_out, int out_size, void* d_ws, size_t ws_size,
                              hipStream_t stream) {
    const float* x      = (const float*)d_in[0];
    const int*   srcL   = (const int*)d_in[1];
    const int*   dstL   = (const int*)d_in[2];
    const float* gcn_w0 = (const float*)d_in[3];
    const float* bn_g0  = (const float*)d_in[5];
    const float* bn_b0  = (const float*)d_in[6];
    const float* gcn_w1 = (const float*)d_in[7];
    const float* bn_g1  = (const float*)d_in[9];
    const float* bn_b1  = (const float*)d_in[10];
    const float* gcn_w2 = (const float*)d_in[11];
    const float* bn_g2  = (const float*)d_in[13];
    const float* bn_b2  = (const float*)d_in[14];
    const float* sc_w0  = (const float*)d_in[15];
    const float* sc_b0  = (const float*)d_in[16];
    const float* edge_w = (const float*)d_in[17];
    const float* fd_w0  = (const float*)d_in[18];
    const float* fd_b0  = (const float*)d_in[19];
    const float* fd_g0  = (const float*)d_in[20];
    const float* fd_be0 = (const float*)d_in[21];
    const float* fd_w1  = (const float*)d_in[22];
    const float* fd_b1  = (const float*)d_in[23];
    const float* fd_g1  = (const float*)d_in[24];
    const float* fd_be1 = (const float*)d_in[25];
    const float* fd_w2  = (const float*)d_in[26];
    const float* fd_b2  = (const float*)d_in[27];
    const float* ph_w0  = (const float*)d_in[28];
    const float* ph_b0  = (const float*)d_in[29];
    const float* ph_w1  = (const float*)d_in[30];
    const float* ph_b1  = (const float*)d_in[31];

    float* out     = (float*)d_out;
    float* out_z   = out;
    float* out_adj = out + 8388608;
    float* out_xr  = out + 12582912;
    float* out_zg  = out + 16777216;
    float* out_zgm = out + 16842752;

    float* w     = (float*)d_ws;
    float* part  = w;                        // 131072
    float* stats = w + 131072;               // 512
    bf*    wT    = (bf*)(w + 131584);        // 557056 bf16
    bf*    Aadjb = (bf*)(w + 410112);        // 4194304 bf16
    bf*    U4    = (bf*)(w + 2507264);       // 8388608 bf16
    bf*    U1    = (bf*)(w + 6701568);
    bf*    U2    = (bf*)(w + 10895872);
    bf*    U3    = (bf*)(w + 15090176);
    bf*    P1b   = (bf*)(w + 19284480);      // 65536 bf16
    bf*    xb    = (bf*)(w + 19317248);      // 4194304 bf16

    WTpack pk;
    pk.w[0] = {gcn_w0, 128, 256, 0};
    pk.w[1] = {sc_w0,  128, 256, 32768};
    pk.w[2] = {gcn_w1, 256, 256, 65536};
    pk.w[3] = {gcn_w2, 256, 256, 131072};
    pk.w[4] = {edge_w, 256, 256, 196608};
    pk.w[5] = {fd_w0,  256, 256, 262144};
    pk.w[6] = {fd_w1,  256, 256, 327680};
    pk.w[7] = {fd_w2,  256, 128, 393216};
    pk.w[8] = {ph_w0,  256, 256, 425984};
    pk.w[9] = {ph_w1,  256, 256, 491520};

    // zero out_zg early (atomicMax target; harness poisons d_out)
    hipMemsetAsync(out_zg, 0, 65536 * 4, stream);

    // --- prep: adjacency + weight transpose + x->bf16 ---
    k_prep<<<672, 256, 0, stream>>>(srcL, dstL, x, pk, Aadjb, xb, wT);

    // --- layer 0 (grid 256x4): AG0 -> U2, res0 -> U1 ---
    k_fused<2><<<dim3(256, 4), 512, 0, stream>>>(xb, nullptr, nullptr,
                                                 wT + 0, wT + 32768, sc_b0, Aadjb,
                                                 nullptr, U2, U1, part);
    k_bnfin<<<256, 256, 0, stream>>>(part, bn_g0, bn_b0, stats);

    // --- layer 1 (grid 256x2): Z0 -> U3, AG1 -> U4 ---
    k_fused<0><<<dim3(256, 2), 512, 0, stream>>>(U2, U1, stats,
                                                 wT + 65536, nullptr, nullptr, Aadjb,
                                                 U3, U4, nullptr, part);
    k_bnfin<<<256, 256, 0, stream>>>(part, bn_g1, bn_b1, stats);

    // --- layer 2: Z1 -> U1, AG2 -> U2 ---
    k_fused<0><<<dim3(256, 2), 512, 0, stream>>>(U4, U3, stats,
                                                 wT + 131072, nullptr, nullptr, Aadjb,
                                                 U1, U2, nullptr, part);
    k_bnfin<<<256, 256, 0, stream>>>(part, bn_g2, bn_b2, stats);

    // --- BN-apply + L2 + col-max: AG2 (U2), res Z1 (U1) -> out_z, Zn (U3), zg ---
    k_finz<<<dim3(256, 2), 512, 0, stream>>>(U2, stats, U1, out_z, U3,
                                             (unsigned*)out_zg);

    // --- edge decoder + fd0 + ph0, one dispatch ---
    k_edfd<<<772, 512, 0, stream>>>(U3, wT + 196608, wT + 262144, fd_b0,
                                    out_zg, wT + 425984, ph_b0,
                                    out_adj, U4, part, P1b);
    k_bnfin<<<256, 256, 0, stream>>>(part, fd_g0, fd_be0, stats);

    // --- feature decoder (fd1, fd2) ---
    MG<2, 1, true, true, false>(stream, U4, wT + 327680, fd_b1, stats,
                                nullptr, U2, part, NN, HD, HD, 256);
    k_bnfin<<<256, 256, 0, stream>>>(part, fd_g1, fd_be1, stats);
    MG<1, 0, false, true, false>(stream, U2, wT + 393216, fd_b2, stats,
                                 out_xr, nullptr, nullptr, NN, 128, HD, 128);

    // --- pooling head tail (ph1 reads P1b from edfd's ph0) ---
    MG<1, 0, false, false, false>(stream, P1b, wT + 491520, ph_b1, nullptr,
                                  out_zgm, nullptr, nullptr, 256, 256, 256, 256);
}

// Round 18
// 173.536 us; speedup vs baseline: 3.3745x; 1.0112x over previous
//
#include <hip/hip_runtime.h>
#include <hip/hip_bf16.h>

using bf = __hip_bfloat16;
typedef __attribute__((ext_vector_type(8))) short s8;
typedef __attribute__((ext_vector_type(4))) float f4;

constexpr int NN  = 32768;
constexpr int HD  = 256;

__device__ __forceinline__ float u2f(unsigned short h) {
    union { unsigned u; float f; } x; x.u = ((unsigned)h) << 16;
    return x.f;
}
__device__ __forceinline__ unsigned short f2u(float f) {
    union { float f; unsigned u; } x; x.f = f;
    unsigned r = x.u + 0x7FFF + ((x.u >> 16) & 1);
    return (unsigned short)(r >> 16);
}
__device__ __forceinline__ bf f2bf(float f) {
    unsigned short h = f2u(f);
    return *reinterpret_cast<bf*>(&h);
}
__device__ __forceinline__ float bf2f(bf b) {
    return u2f(*reinterpret_cast<unsigned short*>(&b));
}

__device__ __forceinline__ int swz(int row, int slot) {      // 64-col rows
    return row * 64 + ((slot ^ (row & 7)) << 3);
}
__device__ __forceinline__ int swz128(int row, int slot) {   // 128-col rows
    return row * 128 + ((slot ^ (row & 7)) << 3);
}

// async global->LDS, 16B per lane; LDS dest = wave-uniform base + lane*16.
typedef const __attribute__((address_space(1))) unsigned int guint;
typedef __attribute__((address_space(3))) unsigned int luint;
__device__ __forceinline__ void gload16(const void* g, void* l) {
    __builtin_amdgcn_global_load_lds((guint*)g, (luint*)l, 16, 0, 0);
}

// ---------------- prep: adjacency + weight transpose + x cvt, one dispatch ----
struct WTd { const float* src; int K, N, off; };
struct WTpack { WTd w[10]; };

__global__ __launch_bounds__(256) void k_prep(const int* __restrict__ srcL,
                                              const int* __restrict__ dstL,
                                              const float* __restrict__ xf,
                                              WTpack p, bf* __restrict__ A,
                                              bf* __restrict__ xb,
                                              bf* __restrict__ wT) {
    __shared__ __align__(16) float shm[8320];
    int b = blockIdx.x, t = threadIdx.x;
    if (b < 256) {
        float* sT = shm;
        float* sdin = shm + 8192;
        int g = b;
        const int* sg = srcL + (g << 11);
        const int* dg = dstL + (g << 11);
        if (t < 128) sdin[t] = 0.f;
        __syncthreads();
        for (int e = t; e < 2048; e += 256) atomicAdd(&sdin[dg[e]], 1.0f);
        __syncthreads();
        if (t < 128) sdin[t] = rsqrtf(sdin[t] + 1.0f);
        __syncthreads();
        bf* out = A + ((long)g << 14);
        for (int half = 0; half < 2; ++half) {
            for (int i = t; i < 8192; i += 256) sT[i] = 0.f;
            __syncthreads();
            for (int e = t; e < 2048; e += 256) {
                int s = sg[e], d = dg[e];
                if ((s >> 6) == half)
                    atomicAdd(&sT[(d << 6) + (s & 63)], sdin[s] * sdin[d]);
            }
            __syncthreads();
            if (t < 128 && (t >> 6) == half)
                sT[(t << 6) + (t & 63)] += sdin[t] * sdin[t];
            __syncthreads();
            for (int i4 = t; i4 < 2048; i4 += 256) {
                int d = i4 >> 4, c4 = (i4 & 15) * 4;
                float4 v = *(float4*)&sT[(d << 6) + c4];
                ushort4 u = make_ushort4(f2u(v.x), f2u(v.y), f2u(v.z), f2u(v.w));
                *(ushort4*)&out[(d << 7) + (half << 6) + c4] = u;
            }
            __syncthreads();
        }
    } else if (b < 416) {
        int idx = b - 256;
        WTd d = p.w[idx >> 4];
        int rem = idx & 15;
        int n0 = (rem & 3) * 64, k0 = (rem >> 2) * 64;
        if (n0 >= d.N || k0 >= d.K) return;
        float (*s)[65] = (float(*)[65])shm;
        int cc = t & 63, rq = t >> 6;
#pragma unroll
        for (int i = 0; i < 16; ++i) {
            int r = i * 4 + rq;
            s[r][cc] = d.src[(long)(k0 + r) * d.N + n0 + cc];
        }
        __syncthreads();
#pragma unroll
        for (int i = 0; i < 16; ++i) {
            int r = i * 4 + rq;
            wT[d.off + (long)(n0 + r) * d.K + k0 + cc] = f2bf(s[cc][r]);
        }
    } else {
        long base = (long)(b - 416) * 16384;
#pragma unroll
        for (int it = 0; it < 16; ++it) {
            long i4 = base + (it * 256 + t) * 4;
            float4 v = *(const float4*)&xf[i4];
            *(ushort4*)&xb[i4] = make_ushort4(f2u(v.x), f2u(v.y), f2u(v.z), f2u(v.w));
        }
    }
}

// ---------------- MFMA helpers (512-thr per-graph kernels) ----------------
__device__ __forceinline__ void mfma_s1(const bf* sA, const bf* sB, f4 (&acc)[4][2],
                                        int wm, int wn, int l15, int kq) {
#pragma unroll
    for (int ks = 0; ks < 2; ++ks) {
        s8 af[4], bg[2];
#pragma unroll
        for (int f = 0; f < 4; ++f)
            af[f] = *(const s8*)&sA[swz(wm * 64 + f * 16 + l15, kq + 4 * ks)];
#pragma unroll
        for (int f = 0; f < 2; ++f)
            bg[f] = *(const s8*)&sB[swz(wn * 32 + f * 16 + l15, kq + 4 * ks)];
#pragma unroll
        for (int fr = 0; fr < 4; ++fr)
#pragma unroll
            for (int fc = 0; fc < 2; ++fc)
                acc[fr][fc] = __builtin_amdgcn_mfma_f32_16x16x32_bf16(
                    af[fr], bg[fc], acc[fr][fc], 0, 0, 0);
    }
}

__device__ __forceinline__ void mfma_s2(const bf* sA, const bf* sB, f4 (&acc)[4][2],
                                        int wm, int wn, int l15, int kq) {
#pragma unroll
    for (int ks = 0; ks < 4; ++ks) {
        s8 af[4], bg[2];
#pragma unroll
        for (int f = 0; f < 4; ++f)
            af[f] = *(const s8*)&sA[swz128(wm * 64 + f * 16 + l15, ks * 4 + kq)];
#pragma unroll
        for (int f = 0; f < 2; ++f)
            bg[f] = *(const s8*)&sB[swz128(wn * 32 + f * 16 + l15, ks * 4 + kq)];
#pragma unroll
        for (int fr = 0; fr < 4; ++fr)
#pragma unroll
            for (int fc = 0; fc < 2; ++fc)
                acc[fr][fc] = __builtin_amdgcn_mfma_f32_16x16x32_bf16(
                    af[fr], bg[fc], acc[fr][fc], 0, 0, 0);
    }
}

__device__ __forceinline__ void tstore(bf* sOut, f4 (&acc)[4][2],
                                       int wm, int wn, int l15, int kq) {
#pragma unroll
    for (int fr = 0; fr < 4; ++fr) {
        int rl = wm * 64 + fr * 16 + kq * 4;
#pragma unroll
        for (int fc = 0; fc < 2; ++fc) {
            int cl = wn * 32 + fc * 16 + l15;
            ushort4 q = make_ushort4(f2u(acc[fr][fc][0]), f2u(acc[fr][fc][1]),
                                     f2u(acc[fr][fc][2]), f2u(acc[fr][fc][3]));
            int off = cl * 128 + (((rl >> 3) ^ (cl & 7)) << 3) + (rl & 7);
            *(ushort4*)&sOut[off] = q;
        }
    }
}

// ---------------- stage-1 staging step (one 64-col K-slab into dst) ----------------
template <int MODE>
__device__ __forceinline__ void stg1(const bf* Xg, const bf* Rg,
                                     const float* stats, const bf* Wt,
                                     const bf* Wt2, bf* Zout, bf* dst,
                                     int g, int h, int k0, int t, int lane, int w) {
#pragma unroll
    for (int i = 0; i < 2; ++i) {
        if constexpr (MODE == 0) {
            int sdx = i * 512 + t;
            int row = sdx >> 3, sl = sdx & 7;
            int c = k0 + sl * 8;
            s8 av = *(const s8*)&Xg[row * 256 + c];
            s8 rv = *(const s8*)&Rg[row * 256 + c];
            float4 sc0 = *(const float4*)&stats[c];
            float4 sc1 = *(const float4*)&stats[c + 4];
            float4 sh0 = *(const float4*)&stats[256 + c];
            float4 sh1 = *(const float4*)&stats[256 + c + 4];
            float scv[8] = {sc0.x, sc0.y, sc0.z, sc0.w, sc1.x, sc1.y, sc1.z, sc1.w};
            float shv[8] = {sh0.x, sh0.y, sh0.z, sh0.w, sh1.x, sh1.y, sh1.z, sh1.w};
            unsigned short* u = (unsigned short*)&av;
            const unsigned short* ru = (const unsigned short*)&rv;
#pragma unroll
            for (int j = 0; j < 8; ++j) {
                float v = fmaf(u2f(u[j]), scv[j], shv[j]);
                v = fmaxf(v, 0.f) + u2f(ru[j]);
                u[j] = f2u(fmaxf(v, 0.f));
            }
            if (h == 0)
                *(s8*)&Zout[(long)g * 32768 + row * 256 + c] = av;
            *(s8*)&dst[swz(row, sl)] = av;
        } else {
            int r0 = i * 64 + 8 * w;
            int rw = r0 + (lane >> 3);
            int ps = ((lane & 7) ^ (rw & 7)) << 3;
            gload16(&Xg[rw * 128 + k0 + ps], &dst[r0 * 64]);
        }
        {
            int r0 = i * 64 + 8 * w;
            int rw = r0 + (lane >> 3);
            int ps = ((lane & 7) ^ (rw & 7)) << 3;
            const bf* bsrc;
            if constexpr (MODE == 0)
                bsrc = &Wt[(h * 128 + rw) * 256 + k0 + ps];
            else {
                const bf* Wsrc = (h < 2) ? Wt : Wt2;
                bsrc = &Wsrc[((h & 1) * 128 + rw) * 128 + k0 + ps];
            }
            gload16(bsrc, &dst[8192 + r0 * 64]);
        }
    }
}

// ---------------- fused per-graph kernels (double-buffered stage 1) ----------------
// MODE 0 (grid 256x2): GCN layer, phase hb = blockIdx.y (independent col-halves)
// MODE 2 (grid 256x4): layer 0; phases 0,1 = GCN halves; 2,3 = shortcut halves
template <int MODE>
__global__ __launch_bounds__(512) void k_fused(
    const bf* __restrict__ Xin,
    const bf* __restrict__ Res, const float* __restrict__ stats,
    const bf* __restrict__ Wt, const bf* __restrict__ Wt2,
    const float* __restrict__ scb, const bf* __restrict__ Adj,
    bf* __restrict__ Zout, bf* __restrict__ AG, bf* __restrict__ ResOut,
    float* __restrict__ part) {
    __shared__ __align__(16) bf sOut[16384];
    __shared__ __align__(16) bf sStg[16384];
    const int g = blockIdx.x;
    const int h = blockIdx.y;
    const int t = threadIdx.x;
    const int lane = t & 63, w = t >> 6;
    const int wm = w >> 2, wn = w & 3;
    const int l15 = lane & 15, kq = lane >> 4;
    constexpr int KS1 = (MODE == 2) ? 128 : 256;
    constexpr int NK = KS1 / 64;
    const bf* Xg = Xin + (long)g * ((MODE == 2) ? 16384 : 32768);
    const bf* Rg = (MODE == 0) ? Res + (long)g * 32768 : nullptr;

    // ---- stage 1: double-buffered (sStg even, sOut odd); one barrier per K-step ----
    f4 acc1[4][2] = {};
    stg1<MODE>(Xg, Rg, stats, Wt, Wt2, Zout, sStg, g, h, 0, t, lane, w);
    __syncthreads();
#pragma unroll
    for (int k = 0; k < NK; ++k) {
        bf* cur = (k & 1) ? sOut : sStg;
        if (k + 1 < NK)
            stg1<MODE>(Xg, Rg, stats, Wt, Wt2, Zout, (k & 1) ? sStg : sOut,
                       g, h, (k + 1) * 64, t, lane, w);
        mfma_s1(cur, cur + 8192, acc1, wm, wn, l15, kq);
        __syncthreads();
    }
    if (MODE == 2 && h >= 2) {
        // shortcut: direct row-major write + bias
#pragma unroll
        for (int fr = 0; fr < 4; ++fr) {
            int rl = wm * 64 + fr * 16 + kq * 4;
#pragma unroll
            for (int fc = 0; fc < 2; ++fc) {
                int cl = wn * 32 + fc * 16 + l15;
                float bv = scb[(h - 2) * 128 + cl];
#pragma unroll
                for (int i = 0; i < 4; ++i)
                    ResOut[(long)(g * 128 + rl + i) * 256 + (h - 2) * 128 + cl] =
                        f2bf(acc1[fr][fc][i] + bv);
            }
        }
        return;
    }
    // ---- HT transposed into sStg (last stage-1 reads were from sOut); Adj into sOut ----
    tstore(sStg, acc1, wm, wn, l15, kq);
#pragma unroll
    for (int i = 0; i < 4; ++i) {
        int r0 = i * 32 + 4 * w;
        int rw = r0 + (lane >> 4);
        int ps = ((lane & 15) ^ (rw & 7)) << 3;
        gload16(&Adj[((long)g << 14) + rw * 128 + ps], &sOut[r0 * 128]);
    }
    __syncthreads();
    f4 acc2[4][2] = {};
    mfma_s2(sOut, sStg, acc2, wm, wn, l15, kq);
    // ---- AG write + BN partials ----
    float ps[2] = {0.f, 0.f}, ps2[2] = {0.f, 0.f};
#pragma unroll
    for (int fr = 0; fr < 4; ++fr) {
        int rl = wm * 64 + fr * 16 + kq * 4;
#pragma unroll
        for (int fc = 0; fc < 2; ++fc) {
            int cl = wn * 32 + fc * 16 + l15;
#pragma unroll
            for (int i = 0; i < 4; ++i) {
                float v = acc2[fr][fc][i];
                ps[fc] += v; ps2[fc] += v * v;
                AG[(long)(g * 128 + rl + i) * 256 + (h & 1) * 128 + cl] = f2bf(v);
            }
        }
    }
    __syncthreads();
    float* scr = (float*)sStg;
#pragma unroll
    for (int fc = 0; fc < 2; ++fc) {
        ps[fc] += __shfl_xor(ps[fc], 16);  ps[fc] += __shfl_xor(ps[fc], 32);
        ps2[fc] += __shfl_xor(ps2[fc], 16); ps2[fc] += __shfl_xor(ps2[fc], 32);
    }
    if (lane < 16) {
#pragma unroll
        for (int fc = 0; fc < 2; ++fc) {
            int c = wn * 32 + fc * 16 + lane;
            scr[(c * 2 + wm) * 2 + 0] = ps[fc];
            scr[(c * 2 + wm) * 2 + 1] = ps2[fc];
        }
    }
    __syncthreads();
    if (t < 256) {
        int col = t & 127, s = t >> 7;
        part[(long)((h & 1) * 256 + g) * 256 + s * 128 + col] =
            scr[(col * 2 + 0) * 2 + s] + scr[(col * 2 + 1) * 2 + s];
    }
}

// ---------------- edge decoder + fd0 + ph0, one dispatch (772 blocks) ----------------
// All three paths double-buffered (sStg even slabs, sOut odd slabs).
__global__ __launch_bounds__(512) void k_edfd(
    const bf* __restrict__ Zn, const bf* __restrict__ ewT,
    const bf* __restrict__ fdw, const float* __restrict__ fdb,
    const float* __restrict__ zgf, const bf* __restrict__ phw,
    const float* __restrict__ phb,
    float* __restrict__ adjout, bf* __restrict__ C, float* __restrict__ part,
    bf* __restrict__ P1b) {
    __shared__ __align__(16) bf sOut[16384];
    __shared__ __align__(16) bf sStg[16384];
    const int t = threadIdx.x;
    const int lane = t & 63, w = t >> 6;
    const int wm = w >> 2, wn = w & 3;
    const int l15 = lane & 15, kq = lane >> 4;
    if (blockIdx.x >= 768) {
        // ---- ph0: P1 = relu(zg @ phw^T + phb), zg f32 [256][256] ----
        int bb = blockIdx.x - 768;
        int gz = bb & 1, h = bb >> 1;
        auto stgP = [&](bf* dst, int k0) {
#pragma unroll
            for (int i = 0; i < 2; ++i) {
                int sdx = i * 512 + t;
                int row = sdx >> 3, sl = sdx & 7;
                int c = k0 + sl * 8;
                const float* src = zgf + (long)(gz * 128 + row) * 256 + c;
                float4 f0 = *(const float4*)src;
                float4 f1 = *(const float4*)(src + 4);
                unsigned short u[8] = {f2u(f0.x), f2u(f0.y), f2u(f0.z), f2u(f0.w),
                                       f2u(f1.x), f2u(f1.y), f2u(f1.z), f2u(f1.w)};
                *(s8*)&dst[swz(row, sl)] = *(s8*)u;
                *(s8*)&dst[8192 + swz(row, sl)] =
                    *(const s8*)&phw[(h * 128 + row) * 256 + c];
            }
        };
        f4 acc[4][2] = {};
        stgP(sStg, 0);
        __syncthreads();
#pragma unroll
        for (int k = 0; k < 4; ++k) {
            bf* cur = (k & 1) ? sOut : sStg;
            if (k + 1 < 4) stgP((k & 1) ? sStg : sOut, (k + 1) * 64);
            mfma_s1(cur, cur + 8192, acc, wm, wn, l15, kq);
            __syncthreads();
        }
#pragma unroll
        for (int fr = 0; fr < 4; ++fr) {
            int rl = wm * 64 + fr * 16 + kq * 4;
#pragma unroll
            for (int fc = 0; fc < 2; ++fc) {
                int cl = wn * 32 + fc * 16 + l15;
                float bv = phb[h * 128 + cl];
#pragma unroll
                for (int i = 0; i < 4; ++i)
                    P1b[(long)(gz * 128 + rl + i) * 256 + h * 128 + cl] =
                        f2bf(fmaxf(acc[fr][fc][i] + bv, 0.f));
            }
        }
        return;
    }
    if (blockIdx.x >= 256) {
        // ---- fd0: C = relu(Zn @ fdw^T + fdb) + BN partials ----
        int bb = blockIdx.x - 256;
        int g = bb & 255, h = bb >> 8;
        const bf* Zg = Zn + (long)g * 32768;
        auto stgF = [&](bf* dst, int k0) {
#pragma unroll
            for (int i = 0; i < 2; ++i) {
                int sdx = i * 512 + t;
                int row = sdx >> 3, sl = sdx & 7;
                int c = k0 + sl * 8;
                *(s8*)&dst[swz(row, sl)] = *(const s8*)&Zg[row * 256 + c];
                *(s8*)&dst[8192 + swz(row, sl)] =
                    *(const s8*)&fdw[(h * 128 + row) * 256 + c];
            }
        };
        f4 acc[4][2] = {};
        stgF(sStg, 0);
        __syncthreads();
#pragma unroll
        for (int k = 0; k < 4; ++k) {
            bf* cur = (k & 1) ? sOut : sStg;
            if (k + 1 < 4) stgF((k & 1) ? sStg : sOut, (k + 1) * 64);
            mfma_s1(cur, cur + 8192, acc, wm, wn, l15, kq);
            __syncthreads();
        }
        float ps[2] = {0.f, 0.f}, ps2[2] = {0.f, 0.f};
#pragma unroll
        for (int fr = 0; fr < 4; ++fr) {
            int rl = wm * 64 + fr * 16 + kq * 4;
#pragma unroll
            for (int fc = 0; fc < 2; ++fc) {
                int cl = wn * 32 + fc * 16 + l15;
                float bv = fdb[h * 128 + cl];
#pragma unroll
                for (int i = 0; i < 4; ++i) {
                    float v = fmaxf(acc[fr][fc][i] + bv, 0.f);
                    ps[fc] += v; ps2[fc] += v * v;
                    C[(long)(g * 128 + rl + i) * 256 + h * 128 + cl] = f2bf(v);
                }
            }
        }
        __syncthreads();
        float* scr = (float*)sStg;
#pragma unroll
        for (int fc = 0; fc < 2; ++fc) {
            ps[fc] += __shfl_xor(ps[fc], 16);  ps[fc] += __shfl_xor(ps[fc], 32);
            ps2[fc] += __shfl_xor(ps2[fc], 16); ps2[fc] += __shfl_xor(ps2[fc], 32);
        }
        if (lane < 16) {
#pragma unroll
            for (int fc = 0; fc < 2; ++fc) {
                int c = wn * 32 + fc * 16 + lane;
                scr[(c * 2 + wm) * 2 + 0] = ps[fc];
                scr[(c * 2 + wm) * 2 + 1] = ps2[fc];
            }
        }
        __syncthreads();
        if (t < 256) {
            int col = t & 127, s = t >> 7;
            part[(long)(h * 256 + g) * 256 + s * 128 + col] =
                scr[(col * 2 + 0) * 2 + s] + scr[(col * 2 + 1) * 2 + s];
        }
        return;
    }
    // ---- edge decoder ----
    const int g = blockIdx.x;
    const bf* Xg = Zn + (long)g * 32768;
    f4 acc2[4][2] = {};
    for (int h = 0; h < 2; ++h) {
        auto stgE = [&](bf* dst, int k0) {
#pragma unroll
            for (int i = 0; i < 2; ++i) {
                int sdx = i * 512 + t;
                int row = sdx >> 3, sl = sdx & 7;
                int c = k0 + sl * 8;
                *(s8*)&dst[swz(row, sl)] = *(const s8*)&ewT[(h * 128 + row) * 256 + c];
                *(s8*)&dst[8192 + swz(row, sl)] = *(const s8*)&Xg[row * 256 + c];
            }
        };
        f4 acc1[4][2] = {};
        stgE(sStg, 0);
        __syncthreads();
#pragma unroll
        for (int k = 0; k < 4; ++k) {
            bf* cur = (k & 1) ? sOut : sStg;
            if (k + 1 < 4) stgE((k & 1) ? sStg : sOut, (k + 1) * 64);
            mfma_s1(cur, cur + 8192, acc1, wm, wn, l15, kq);
            __syncthreads();
        }
        // last stage-1 reads were from sOut -> E^T into sStg, X columns into sOut
        tstore(sStg, acc1, wm, wn, l15, kq);
#pragma unroll
        for (int i = 0; i < 4; ++i) {
            int sdx = i * 512 + t;
            int row = sdx >> 4, sl = sdx & 15;
            *(s8*)&sOut[swz128(row, sl)] = *(const s8*)&Xg[row * 256 + h * 128 + sl * 8];
        }
        __syncthreads();
        mfma_s2(sOut, sStg, acc2, wm, wn, l15, kq);
        __syncthreads();
    }
#pragma unroll
    for (int fr = 0; fr < 4; ++fr) {
        int rl = wm * 64 + fr * 16 + kq * 4;
#pragma unroll
        for (int fc = 0; fc < 2; ++fc) {
            int cl = wn * 32 + fc * 16 + l15;
            float vv[4];
#pragma unroll
            for (int i = 0; i < 4; ++i) {
                float v = 1.f / (1.f + __expf(-acc2[fr][fc][i]));
                if (cl == rl + i) v = 0.f;
                vv[i] = v;
            }
            float4 o; o.x = vv[0]; o.y = vv[1]; o.z = vv[2]; o.w = vv[3];
            *(float4*)&adjout[((long)g << 14) + cl * 128 + rl] = o;
        }
    }
}

// ---------------- MFMA GEMM (fd1/fd2/ph1) ----------------
template <int EPI, int OUT, bool PART, bool BNA, bool AF32>
__global__ __launch_bounds__(256) void mg(
    const void* __restrict__ Av, const bf* __restrict__ BT,
    const float* __restrict__ bias, const float* __restrict__ bnstats,
    float* __restrict__ Cf, bf* __restrict__ Cb, float* __restrict__ part,
    int M, int N, int K, int ldc) {
    __shared__ __align__(16) bf sAl[128 * 64];
    __shared__ __align__(16) bf sBl[128 * 64];
    const int m0 = blockIdx.y * 128, n0 = blockIdx.x * 128;
    const bf* Bb = BT + (long)n0 * K;
    const int t = threadIdx.x;
    const int lane = t & 63;
    const int w = t >> 6;
    const int wm = (w >> 1) * 64, wn = (w & 1) * 64;
    const int fr16 = lane & 15, kq = lane >> 4;
    f4 acc[4][4] = {};
    for (int k0 = 0; k0 < K; k0 += 64) {
#pragma unroll
        for (int i = 0; i < 4; ++i) {
            int sdx = i * 256 + t;
            int row = sdx >> 3, sl = sdx & 7;
            s8 av;
            if constexpr (AF32) {
                const float* src = (const float*)Av + (long)(m0 + row) * K + k0 + sl * 8;
                float4 f0 = *(const float4*)src;
                float4 f1 = *(const float4*)(src + 4);
                unsigned short u[8] = {f2u(f0.x), f2u(f0.y), f2u(f0.z), f2u(f0.w),
                                       f2u(f1.x), f2u(f1.y), f2u(f1.z), f2u(f1.w)};
                av = *(s8*)u;
            } else {
                av = *(const s8*)&((const bf*)Av)[(long)(m0 + row) * K + k0 + sl * 8];
                if constexpr (BNA) {
                    int c = k0 + sl * 8;
                    float4 sc0 = *(const float4*)&bnstats[c];
                    float4 sc1 = *(const float4*)&bnstats[c + 4];
                    float4 sh0 = *(const float4*)&bnstats[256 + c];
                    float4 sh1 = *(const float4*)&bnstats[256 + c + 4];
                    float scv[8] = {sc0.x, sc0.y, sc0.z, sc0.w, sc1.x, sc1.y, sc1.z, sc1.w};
                    float shv[8] = {sh0.x, sh0.y, sh0.z, sh0.w, sh1.x, sh1.y, sh1.z, sh1.w};
                    unsigned short* u = (unsigned short*)&av;
#pragma unroll
                    for (int j = 0; j < 8; ++j)
                        u[j] = f2u(fmaf(u2f(u[j]), scv[j], shv[j]));
                }
            }
            *(s8*)&sAl[swz(row, sl)] = av;
            *(s8*)&sBl[swz(row, sl)] = *(const s8*)&Bb[(long)row * K + k0 + sl * 8];
        }
        __syncthreads();
#pragma unroll
        for (int ks = 0; ks < 2; ++ks) {
            s8 af[4], bg[4];
#pragma unroll
            for (int f = 0; f < 4; ++f) {
                af[f] = *(const s8*)&sAl[swz(wm + f * 16 + fr16, kq + 4 * ks)];
                bg[f] = *(const s8*)&sBl[swz(wn + f * 16 + fr16, kq + 4 * ks)];
            }
#pragma unroll
            for (int fr = 0; fr < 4; ++fr)
#pragma unroll
                for (int fc = 0; fc < 4; ++fc)
                    acc[fr][fc] = __builtin_amdgcn_mfma_f32_16x16x32_bf16(
                        af[fr], bg[fc], acc[fr][fc], 0, 0, 0);
        }
        __syncthreads();
    }
    float ps[4], ps2[4];
    if (PART) {
#pragma unroll
        for (int fc = 0; fc < 4; ++fc) { ps[fc] = 0.f; ps2[fc] = 0.f; }
    }
#pragma unroll
    for (int fr = 0; fr < 4; ++fr) {
        int rl = wm + fr * 16 + (lane >> 4) * 4;
#pragma unroll
        for (int fc = 0; fc < 4; ++fc) {
            int cl = wn + fc * 16 + (lane & 15);
            int col = n0 + cl;
            float bv = bias[col];
#pragma unroll
            for (int i = 0; i < 4; ++i) {
                float v = acc[fr][fc][i] + bv;
                if (EPI == 2) v = fmaxf(v, 0.f);
                if (PART) { ps[fc] += v; ps2[fc] += v * v; }
                if (OUT == 0) Cf[(long)(m0 + rl + i) * ldc + col] = v;
                if (OUT == 1) Cb[(long)(m0 + rl + i) * ldc + col] = f2bf(v);
            }
        }
    }
    if (PART) {
        __syncthreads();
        float* scr = (float*)sAl;
#pragma unroll
        for (int fc = 0; fc < 4; ++fc) {
            ps[fc] += __shfl_xor(ps[fc], 16);  ps[fc] += __shfl_xor(ps[fc], 32);
            ps2[fc] += __shfl_xor(ps2[fc], 16); ps2[fc] += __shfl_xor(ps2[fc], 32);
        }
        if (lane < 16) {
#pragma unroll
            for (int fc = 0; fc < 4; ++fc) {
                scr[(w * 2 + 0) * 64 + fc * 16 + lane] = ps[fc];
                scr[(w * 2 + 1) * 64 + fc * 16 + lane] = ps2[fc];
            }
        }
        __syncthreads();
        int id = blockIdx.x * gridDim.y + blockIdx.y;   // gridDim = (2, 256)
        int stat = t >> 7, c = t & 127;
        int ci = c & 63, half = c >> 6;
        float v = scr[(half * 2 + stat) * 64 + ci] + scr[((half + 2) * 2 + stat) * 64 + ci];
        part[(long)id * 256 + stat * 128 + c] = v;
    }
}

// ---------------- batchnorm finalize -> (scale, shift) ----------------
__global__ void k_bnfin(const float* __restrict__ part, const float* __restrict__ gam,
                        const float* __restrict__ bet, float* __restrict__ stats) {
    int ch = blockIdx.x;
    int half = ch >> 7, cc = ch & 127;
    int t = threadIdx.x;
    __shared__ float2 sm[256];
    const float* p = part + (long)(half * 256 + t) * 256;
    sm[t] = make_float2(p[cc], p[128 + cc]);
    __syncthreads();
    for (int s = 128; s > 0; s >>= 1) {
        if (t < s) { sm[t].x += sm[t + s].x; sm[t].y += sm[t + s].y; }
        __syncthreads();
    }
    if (t == 0) {
        float m = sm[0].x / (float)NN;
        float var = sm[0].y / (float)NN - m * m;
        float sc = rsqrtf(var + 1e-5f) * gam[ch];
        stats[ch]       = sc;
        stats[256 + ch] = bet[ch] - m * sc;
    }
}

// ---------------- final: BN-apply + residual + relu + L2-norm + col-max ----------------
__global__ __launch_bounds__(512) void k_finz(
    const bf* __restrict__ X, const float* __restrict__ stats,
    const bf* __restrict__ res, float* __restrict__ outz, bf* __restrict__ Znb,
    unsigned* __restrict__ zgu) {
    int g = blockIdx.x, half = blockIdx.y;
    int t = threadIdx.x;
    int lane = t & 63, w = t >> 6;
    int c4 = lane * 4;
    float4 sc = *(const float4*)&stats[c4];
    float4 sh = *(const float4*)&stats[256 + c4];
    float scv[4] = {sc.x, sc.y, sc.z, sc.w};
    float shv[4] = {sh.x, sh.y, sh.z, sh.w};
    float cmax[4] = {0.f, 0.f, 0.f, 0.f};
#pragma unroll
    for (int it = 0; it < 8; ++it) {
        int r = half * 64 + w * 8 + it;
        long i = (long)(g * 128 + r) * 256 + c4;
        ushort4 xv = *(const ushort4*)(X + i);
        ushort4 rv = *(const ushort4*)(res + i);
        unsigned short xs[4] = {xv.x, xv.y, xv.z, xv.w};
        unsigned short rs[4] = {rv.x, rv.y, rv.z, rv.w};
        float v[4];
        float s = 0.f;
#pragma unroll
        for (int j = 0; j < 4; ++j) {
            float vv = fmaf(u2f(xs[j]), scv[j], shv[j]);
            vv = fmaxf(vv, 0.f) + u2f(rs[j]);
            vv = fmaxf(vv, 0.f);
            v[j] = vv;
            s += vv * vv;
        }
#pragma unroll
        for (int o = 1; o < 64; o <<= 1) s += __shfl_xor(s, o);
        float den = fmaxf(sqrtf(s), 1e-12f);
        float4 fo;
        unsigned short us[4];
#pragma unroll
        for (int j = 0; j < 4; ++j) {
            float o = v[j] / den;
            ((float*)&fo)[j] = o;
            us[j] = f2u(o);
            cmax[j] = fmaxf(cmax[j], o);
        }
        *(float4*)(outz + i) = fo;
        *(ushort4*)(Znb + i) = make_ushort4(us[0], us[1], us[2], us[3]);
    }
    __shared__ float pm[8][256];
#pragma unroll
    for (int j = 0; j < 4; ++j) pm[w][c4 + j] = cmax[j];
    __syncthreads();
    if (t < 256) {
        float m = fmaxf(pm[0][t], pm[1][t]);
#pragma unroll
        for (int ww = 2; ww < 8; ++ww) m = fmaxf(m, pm[ww][t]);
        atomicMax(&zgu[g * 256 + t], __float_as_uint(m));
    }
}

// ---------------- host ----------------
template <int EPI, int OUT, bool PART, bool BNA, bool AF32>
static void MG(hipStream_t st, const void* A, const bf* BT, const float* bias,
               const float* bnstats, float* Cf, bf* Cb, float* part,
               int M, int N, int K, int ldc) {
    dim3 g(N / 128, M / 128, 1);
    mg<EPI, OUT, PART, BNA, AF32><<<g, 256, 0, st>>>(A, BT, bias, bnstats, Cf, Cb, part,
                                                     M, N, K, ldc);
}

extern "C" void kernel_launch(void* const* d_in, const int* in_sizes, int n_in,
                              void* d_out, int out_size, void* d_ws, size_t ws_size,
                              hipStream_t stream) {
    const float* x      = (const float*)d_in[0];
    const int*   srcL   = (const int*)d_in[1];
    const int*   dstL   = (const int*)d_in[2];
    const float* gcn_w0 = (const float*)d_in[3];
    const float* bn_g0  = (const float*)d_in[5];
    const float* bn_b0  = (const float*)d_in[6];
    const float* gcn_w1 = (const float*)d_in[7];
    const float* bn_g1  = (const float*)d_in[9];
    const float* bn_b1  = (const float*)d_in[10];
    const float* gcn_w2 = (const float*)d_in[11];
    const float* bn_g2  = (const float*)d_in[13];
    const float* bn_b2  = (const float*)d_in[14];
    const float* sc_w0  = (const float*)d_in[15];
    const float* sc_b0  = (const float*)d_in[16];
    const float* edge_w = (const float*)d_in[17];
    const float* fd_w0  = (const float*)d_in[18];
    const float* fd_b0  = (const float*)d_in[19];
    const float* fd_g0  = (const float*)d_in[20];
    const float* fd_be0 = (const float*)d_in[21];
    const float* fd_w1  = (const float*)d_in[22];
    const float* fd_b1  = (const float*)d_in[23];
    const float* fd_g1  = (const float*)d_in[24];
    const float* fd_be1 = (const float*)d_in[25];
    const float* fd_w2  = (const float*)d_in[26];
    const float* fd_b2  = (const float*)d_in[27];
    const float* ph_w0  = (const float*)d_in[28];
    const float* ph_b0  = (const float*)d_in[29];
    const float* ph_w1  = (const float*)d_in[30];
    const float* ph_b1  = (const float*)d_in[31];

    float* out     = (float*)d_out;
    float* out_z   = out;
    float* out_adj = out + 8388608;
    float* out_xr  = out + 12582912;
    float* out_zg  = out + 16777216;
    float* out_zgm = out + 16842752;

    float* w     = (float*)d_ws;
    float* part  = w;                        // 131072
    float* stats = w + 131072;               // 512
    bf*    wT    = (bf*)(w + 131584);        // 557056 bf16
    bf*    Aadjb = (bf*)(w + 410112);        // 4194304 bf16
    bf*    U4    = (bf*)(w + 2507264);       // 8388608 bf16
    bf*    U1    = (bf*)(w + 6701568);
    bf*    U2    = (bf*)(w + 10895872);
    bf*    U3    = (bf*)(w + 15090176);
    bf*    P1b   = (bf*)(w + 19284480);      // 65536 bf16
    bf*    xb    = (bf*)(w + 19317248);      // 4194304 bf16

    WTpack pk;
    pk.w[0] = {gcn_w0, 128, 256, 0};
    pk.w[1] = {sc_w0,  128, 256, 32768};
    pk.w[2] = {gcn_w1, 256, 256, 65536};
    pk.w[3] = {gcn_w2, 256, 256, 131072};
    pk.w[4] = {edge_w, 256, 256, 196608};
    pk.w[5] = {fd_w0,  256, 256, 262144};
    pk.w[6] = {fd_w1,  256, 256, 327680};
    pk.w[7] = {fd_w2,  256, 128, 393216};
    pk.w[8] = {ph_w0,  256, 256, 425984};
    pk.w[9] = {ph_w1,  256, 256, 491520};

    // zero out_zg early (atomicMax target; harness poisons d_out)
    hipMemsetAsync(out_zg, 0, 65536 * 4, stream);

    // --- prep: adjacency + weight transpose + x->bf16 ---
    k_prep<<<672, 256, 0, stream>>>(srcL, dstL, x, pk, Aadjb, xb, wT);

    // --- layer 0 (grid 256x4): AG0 -> U2, res0 -> U1 ---
    k_fused<2><<<dim3(256, 4), 512, 0, stream>>>(xb, nullptr, nullptr,
                                                 wT + 0, wT + 32768, sc_b0, Aadjb,
                                                 nullptr, U2, U1, part);
    k_bnfin<<<256, 256, 0, stream>>>(part, bn_g0, bn_b0, stats);

    // --- layer 1 (grid 256x2): Z0 -> U3, AG1 -> U4 ---
    k_fused<0><<<dim3(256, 2), 512, 0, stream>>>(U2, U1, stats,
                                                 wT + 65536, nullptr, nullptr, Aadjb,
                                                 U3, U4, nullptr, part);
    k_bnfin<<<256, 256, 0, stream>>>(part, bn_g1, bn_b1, stats);

    // --- layer 2: Z1 -> U1, AG2 -> U2 ---
    k_fused<0><<<dim3(256, 2), 512, 0, stream>>>(U4, U3, stats,
                                                 wT + 131072, nullptr, nullptr, Aadjb,
                                                 U1, U2, nullptr, part);
    k_bnfin<<<256, 256, 0, stream>>>(part, bn_g2, bn_b2, stats);

    // --- BN-apply + L2 + col-max: AG2 (U2), res Z1 (U1) -> out_z, Zn (U3), zg ---
    k_finz<<<dim3(256, 2), 512, 0, stream>>>(U2, stats, U1, out_z, U3,
                                             (unsigned*)out_zg);

    // --- edge decoder + fd0 + ph0, one dispatch ---
    k_edfd<<<772, 512, 0, stream>>>(U3, wT + 196608, wT + 262144, fd_b0,
                                    out_zg, wT + 425984, ph_b0,
                                    out_adj, U4, part, P1b);
    k_bnfin<<<256, 256, 0, stream>>>(part, fd_g0, fd_be0, stats);

    // --- feature decoder (fd1, fd2) ---
    MG<2, 1, true, true, false>(stream, U4, wT + 327680, fd_b1, stats,
                                nullptr, U2, part, NN, HD, HD, 256);
    k_bnfin<<<256, 256, 0, stream>>>(part, fd_g1, fd_be1, stats);
    MG<1, 0, false, true, false>(stream, U2, wT + 393216, fd_b2, stats,
                                 out_xr, nullptr, nullptr, NN, 128, HD, 128);

    // --- pooling head tail (ph1 reads P1b from edfd's ph0) ---
    MG<1, 0, false, false, false>(stream, P1b, wT + 491520, ph_b1, nullptr,
                                  out_zgm, nullptr, nullptr, 256, 256, 256, 256);
}